// Round 8
// baseline (783.753 us; speedup 1.0000x reference)
//
#include <hip/hip_runtime.h>

// Problem constants: B=2, T=4096, D=2048, N=8 heads, K=1 kv-head, H=256
#define T_SEQ 4096
#define D_MODEL 2048
#define N_HEADS 8
#define HDIM 256

typedef unsigned int uint32;
typedef unsigned short u16;
typedef __attribute__((ext_vector_type(8))) short short8;  // 8 bf16 (4 VGPRs)
typedef __attribute__((ext_vector_type(4))) float f32x4;
typedef __attribute__((ext_vector_type(4))) uint32 u32x4;

__device__ __forceinline__ float bf2f(u16 v) {
  return __uint_as_float(((uint32)v) << 16);
}
__device__ __forceinline__ u16 f2bf(float f) {
  uint32 u = __float_as_uint(f);
  u += 0x7fffu + ((u >> 16) & 1u);  // round-to-nearest-even
  return (u16)(u >> 16);
}
__device__ __forceinline__ uint32 pkbf(float x, float y) {
  return (uint32)f2bf(x) | ((uint32)f2bf(y) << 16);
}
__device__ __forceinline__ uint2 pack4(const f32x4 v) {
  uint2 r;
  r.x = (uint32)f2bf(v[0]) | ((uint32)f2bf(v[1]) << 16);
  r.y = (uint32)f2bf(v[2]) | ((uint32)f2bf(v[3]) << 16);
  return r;
}
// async global->LDS, 16B per lane; LDS dest must be lane-contiguous.
__device__ __forceinline__ void gload16(const u16* g, u16* l) {
  __builtin_amdgcn_global_load_lds(
      (const __attribute__((address_space(1))) unsigned int*)g,
      (__attribute__((address_space(3))) unsigned int*)l, 16, 0, 0);
}

// ---------------------------------------------------------------------------
// Prep 1: x (f32) -> xb (bf16), row-major [8192][2048].
// ---------------------------------------------------------------------------
__global__ __launch_bounds__(256) void convert_x(const float* __restrict__ x,
                                                 u16* __restrict__ xb) {
  const int idx = blockIdx.x * 256 + threadIdx.x;  // 4 elems each
  float4 v = *(const float4*)(x + (size_t)idx * 4);
  uint2 pk;
  pk.x = (uint32)f2bf(v.x) | ((uint32)f2bf(v.y) << 16);
  pk.y = (uint32)f2bf(v.z) | ((uint32)f2bf(v.w) << 16);
  *(uint2*)(xb + (size_t)idx * 4) = pk;
}

// ---------------------------------------------------------------------------
// Prep 2: transpose+convert weights to bf16 B^T layouts:
//   z=0: W_all[d][c] (c<2048: qw head c>>8 col c&255; else kv) -> Wt[c][d]
//   z=1: ow[k][d] (k = n*256+h)                                -> Owt[d][k]
// ---------------------------------------------------------------------------
__global__ __launch_bounds__(256) void prep_weights(
    const float* __restrict__ qw, const float* __restrict__ kvw,
    const float* __restrict__ ow, u16* __restrict__ Wt, u16* __restrict__ Owt) {
  __shared__ float Ts[64][65];
  const int t = threadIdx.x;
  const int tx = blockIdx.x, ty = blockIdx.y, z = blockIdx.z;
  const float* src;
  int srcStride;
  u16* dst;
  if (z == 0) {
    const int c0 = tx * 64;
    const float* base = (c0 < 2048)
                            ? qw + (size_t)(c0 >> 8) * D_MODEL * HDIM
                            : kvw + (size_t)((c0 - 2048) >> 8) * D_MODEL * HDIM;
    src = base + (c0 & 255);
    srcStride = HDIM;
    dst = Wt + (size_t)c0 * D_MODEL;
  } else {
    if (tx >= 32) return;
    src = ow + tx * 64;
    srcStride = D_MODEL;
    dst = Owt + (size_t)tx * 64 * D_MODEL;
  }
  const int d0 = ty * 64;
  const int r = t >> 4, c4 = (t & 15) * 4;
#pragma unroll
  for (int i = 0; i < 4; ++i) {
    float4 v = *(const float4*)(src + (size_t)(d0 + r + i * 16) * srcStride + c4);
    *(float4*)&Ts[r + i * 16][c4] = v;
  }
  __syncthreads();
#pragma unroll
  for (int i = 0; i < 4; ++i) {
    const int crow = r + i * 16;  // output row (source col)
    uint2 pk;
    pk.x = (uint32)f2bf(Ts[c4 + 0][crow]) | ((uint32)f2bf(Ts[c4 + 1][crow]) << 16);
    pk.y = (uint32)f2bf(Ts[c4 + 2][crow]) | ((uint32)f2bf(Ts[c4 + 3][crow]) << 16);
    *(uint2*)(dst + (size_t)crow * D_MODEL + d0 + c4) = pk;
  }
}

// ---------------------------------------------------------------------------
// MFMA GEMM 1: [xb 8192x2048 bf16] @ [Wt^T] -> Q/K/V.  cols: 0..2047 Q,
// 2048..2303 K, 2304..2559 V (written transposed Vt[b][h][s]).
// Round 8: XCD-aware bijective block swizzle (T1) for L2 panel reuse.
// ---------------------------------------------------------------------------
__global__ __launch_bounds__(256) void gemm_qkv_mfma(
    const u16* __restrict__ xb, const u16* __restrict__ Wt,
    u16* __restrict__ Qb, u16* __restrict__ Kb, u16* __restrict__ Vt) {
  __shared__ u16 Asm[128][32];
  __shared__ u16 Bsm[128][32];
  const int t = threadIdx.x;
  const int w = t >> 6, l = t & 63, quad = l >> 4, lq = l & 15;
  const int wm = w & 1, wn = w >> 1;
  // XCD swizzle: nwg = 20*64 = 1280 (%8==0 -> bijective).
  const int lb = blockIdx.x + 20 * blockIdx.y;
  const int sw = (lb & 7) * 160 + (lb >> 3);
  const int col0 = (sw % 20) * 128, row0 = (sw / 20) * 128;
  const u16* ga0 = xb + (size_t)(row0 + (t >> 2)) * D_MODEL + (t & 3) * 8;
  const u16* ga1 = ga0 + (size_t)64 * D_MODEL;
  const u16* gb0 = Wt + (size_t)(col0 + (t >> 2)) * D_MODEL + (t & 3) * 8;
  const u16* gb1 = gb0 + (size_t)64 * D_MODEL;
  u16* lA0 = &Asm[0][0] + t * 8;
  u16* lA1 = lA0 + 2048;
  u16* lB0 = &Bsm[0][0] + t * 8;
  u16* lB1 = lB0 + 2048;
  f32x4 acc[4][4];
#pragma unroll
  for (int i = 0; i < 4; ++i)
#pragma unroll
    for (int j = 0; j < 4; ++j) acc[i][j] = (f32x4){0.f, 0.f, 0.f, 0.f};
  for (int k0 = 0; k0 < D_MODEL; k0 += 32) {
    gload16(ga0 + k0, lA0);
    gload16(ga1 + k0, lA1);
    gload16(gb0 + k0, lB0);
    gload16(gb1 + k0, lB1);
    __syncthreads();
    short8 af[4], bf[4];
#pragma unroll
    for (int i = 0; i < 4; ++i)
      af[i] = *(const short8*)&Asm[wm * 64 + i * 16 + lq][quad * 8];
#pragma unroll
    for (int j = 0; j < 4; ++j)
      bf[j] = *(const short8*)&Bsm[wn * 64 + j * 16 + lq][quad * 8];
#pragma unroll
    for (int i = 0; i < 4; ++i)
#pragma unroll
      for (int j = 0; j < 4; ++j)
        acc[i][j] =
            __builtin_amdgcn_mfma_f32_16x16x32_bf16(af[i], bf[j], acc[i][j], 0, 0, 0);
    __syncthreads();
  }
  const int b = row0 >> 12, sbase = row0 & 4095;
#pragma unroll
  for (int i = 0; i < 4; ++i) {
    const int rowloc = wm * 64 + i * 16 + quad * 4;
#pragma unroll
    for (int j = 0; j < 4; ++j) {
      const int col = col0 + wn * 64 + j * 16 + lq;
      if (col < 2048) {
#pragma unroll
        for (int r = 0; r < 4; ++r)
          Qb[(size_t)(row0 + rowloc + r) * 2048 + col] = f2bf(acc[i][j][r]);
      } else if (col < 2304) {
#pragma unroll
        for (int r = 0; r < 4; ++r)
          Kb[(size_t)(row0 + rowloc + r) * HDIM + (col - 2048)] =
              f2bf(acc[i][j][r]);
      } else {
        *(uint2*)(Vt + ((size_t)b * HDIM + col - 2304) * T_SEQ + sbase + rowloc) =
            pack4(acc[i][j]);
      }
    }
  }
}

// ---------------------------------------------------------------------------
// RoPE (in-place on bf16 Q and K) + query scaling by H^-0.5.
// ---------------------------------------------------------------------------
__global__ __launch_bounds__(256) void rope_kernel(u16* __restrict__ Qb,
                                                   u16* __restrict__ Kb,
                                                   const int* __restrict__ segpos) {
  const int bt = blockIdx.x;
  const int tid = threadIdx.x;
  const float fpos = (float)segpos[bt];
  const float k_ln = 9.210340371976184f / 128.0f;  // ln(10000)/(H/2)
  for (int p = tid; p < 1024; p += 256) {
    const int n = p >> 7, i = p & 127;
    const size_t base = (size_t)bt * (N_HEADS * HDIM) + (size_t)n * HDIM;
    const float th = fpos * expf(-(float)i * k_ln);
    float s, c;
    sincosf(th, &s, &c);
    const float f1 = bf2f(Qb[base + i]);
    const float f2 = bf2f(Qb[base + i + 128]);
    Qb[base + i] = f2bf((f1 * c - f2 * s) * 0.0625f);
    Qb[base + i + 128] = f2bf((f2 * c + f1 * s) * 0.0625f);
  }
  if (tid < 128) {
    const int i = tid;
    const size_t base = (size_t)bt * HDIM;
    const float th = fpos * expf(-(float)i * k_ln);
    float s, c;
    sincosf(th, &s, &c);
    const float f1 = bf2f(Kb[base + i]);
    const float f2 = bf2f(Kb[base + i + 128]);
    Kb[base + i] = f2bf(f1 * c - f2 * s);
    Kb[base + i + 128] = f2bf(f2 * c + f1 * s);
  }
}

// ---------------------------------------------------------------------------
// MFMA flash attention (causal, MQA) — Round 8 (resubmit after infra timeout):
// 32 q-rows per wave. PMC evidence (R6): LDS pipe ~74% busy was the binding
// resource; each wave read the full K/V tile per iter for only 16 q-rows.
// Now each wave holds TWO Q groups (qf0/qf1) and two accumulators (O0/O1);
// every K/V fragment read from LDS feeds both groups' MFMAs -> per unit
// work, LDS reads, staging traffic, barriers and vmcnt waits all halve;
// MFMA per wave-iter doubles (32->64). Block = 128-row q-tile (4 waves x
// 32q), paired {31-bid, bid} -> grid 16x8x2 = 256 equal blocks (132 iters).
// Everything else from the verified R6 kernel (swapped QK^T, K/V chunk-XOR
// swizzles, gload_lds dbuf, counted vmcnt(8), shfl_xor select-network P
// exchange, defer-max, setprio) is kept verbatim per group.
// ---------------------------------------------------------------------------
__global__ __launch_bounds__(256, 1) void attn_mfma(const u16* __restrict__ Qb,
                                                    const u16* __restrict__ Kb,
                                                    const u16* __restrict__ Vt,
                                                    u16* __restrict__ Eb) {
  __shared__ u16 KsB[2][8192];  // [buf] 32 s-rows x 256 h (16B chunks swizzled)
  __shared__ u16 VsB[2][8192];  // [buf] 256 h-rows x 32 s (16B chunks swizzled)
  const int t = threadIdx.x;
  const int w = t >> 6, l = t & 63;
  const int quad = l >> 4, lq = l & 15;
  const int sx = lq & 7;
  const int bid = blockIdx.x;  // 0..15
  const int n = blockIdx.y, b = blockIdx.z;
  const u16* kgbase = Kb + (size_t)b * T_SEQ * HDIM;
  const u16* vgbase = Vt + (size_t)b * HDIM * T_SEQ;

  // Per-thread staging geometry: 4 K-chunks + 4 V-chunks of 16B per s-tile.
  // LDS is written linearly (wave-uniform base + lane*16); both K and V
  // carry their inverse swizzle on the global source address.
  int koff[4], voff[4], ldo[4];
#pragma unroll
  for (int p = 0; p < 4; ++p) {
    const int cid = w * 4 + p;              // 16 chunks of 1KB per 16KB tile
    const int krow = 2 * cid + (l >> 5);    // K row 0..31
    const int kchk = (l & 31) ^ (krow & 7); // swizzled 16B chunk within row
    koff[p] = krow * HDIM + kchk * 8;
    const int s_ = cid * 64 + l;            // physical 16B chunk 0..1023
    const int c_ = s_ ^ ((s_ >> 3) & 7);    // logical chunk (involution)
    voff[p] = (c_ >> 2) * T_SEQ + (c_ & 3) * 8;  // V h-row, s-chunk
    ldo[p] = cid * 512 + l * 8;             // u16 offset inside 16KB buffer
  }
  // V read-side swizzled per-lane offset (constant across ntl/iter):
  const int vlx = (lq * 32 + quad * 8) ^ ((lq >> 1) << 3);

  auto stage = [&](int buf, int s0) {
#pragma unroll
    for (int p = 0; p < 4; ++p)
      gload16(kgbase + (size_t)s0 * HDIM + koff[p], &KsB[buf][ldo[p]]);
#pragma unroll
    for (int p = 0; p < 4; ++p)
      gload16(vgbase + (size_t)voff[p] + s0, &VsB[buf][ldo[p]]);
  };

#pragma unroll 1
  for (int ti = 0; ti < 2; ++ti) {
    const int qt = ti ? bid : 31 - bid;  // heavy tile first
    const int q0 = qt * 128;
    const int wrow0 = q0 + w * 32;  // this wave: q-rows wrow0..wrow0+31

    // Q fragments for both 16-row groups (8 chunks of K=32 head-dims each).
    short8 qf0[8], qf1[8];
    {
      const u16* qb0 = Qb +
          (((size_t)b * T_SEQ + wrow0 + lq) * N_HEADS + n) * HDIM + quad * 8;
      const u16* qb1 = qb0 + (size_t)16 * N_HEADS * HDIM;
#pragma unroll
      for (int c = 0; c < 8; ++c) {
        qf0[c] = *(const short8*)(qb0 + c * 32);
        qf1[c] = *(const short8*)(qb1 + c * 32);
      }
    }
    stage(0, 0);

    f32x4 O0[16], O1[16];
#pragma unroll
    for (int i = 0; i < 16; ++i) {
      O0[i] = (f32x4){0.f, 0.f, 0.f, 0.f};
      O1[i] = (f32x4){0.f, 0.f, 0.f, 0.f};
    }
    float m0 = -1e30f, li0 = 0.f;
    float m1 = -1e30f, li1 = 0.f;

    const int nst = 4 * qt + 4;
    int cur = 0;
#pragma unroll 1
    for (int st = 0; st < nst; ++st) {
      const int s0 = st * 32;
      if (st + 1 < nst) {
        stage(cur ^ 1, s0 + 32);
        // current tile's 8 loads are the 8-before-last -> counted wait keeps
        // the prefetch in flight across the barrier.
        asm volatile("s_waitcnt vmcnt(8)" ::: "memory");
      } else {
        asm volatile("s_waitcnt vmcnt(0)" ::: "memory");
      }
      __builtin_amdgcn_s_barrier();
      if (s0 <= wrow0 + 31) {  // wave-uniform skip (both groups fully masked)
        const u16* Kc = &KsB[cur][0];
        f32x4 sa00 = (f32x4){0.f, 0.f, 0.f, 0.f};
        f32x4 sa01 = (f32x4){0.f, 0.f, 0.f, 0.f};
        f32x4 sa10 = (f32x4){0.f, 0.f, 0.f, 0.f};
        f32x4 sa11 = (f32x4){0.f, 0.f, 0.f, 0.f};
        __builtin_amdgcn_s_setprio(1);
#pragma unroll
        for (int c = 0; c < 8; ++c) {
          const int cb = ((c * 4 + quad) ^ sx) * 8;
          short8 k0 = *(const short8*)&Kc[lq * 256 + cb];
          short8 k1 = *(const short8*)&Kc[(16 + lq) * 256 + cb];
          // swapped operands: lane holds S[q=group row lq][s=quad*4+r (+16)]
          sa00 = __builtin_amdgcn_mfma_f32_16x16x32_bf16(k0, qf0[c], sa00, 0, 0, 0);
          sa01 = __builtin_amdgcn_mfma_f32_16x16x32_bf16(k1, qf0[c], sa01, 0, 0, 0);
          sa10 = __builtin_amdgcn_mfma_f32_16x16x32_bf16(k0, qf1[c], sa10, 0, 0, 0);
          sa11 = __builtin_amdgcn_mfma_f32_16x16x32_bf16(k1, qf1[c], sa11, 0, 0, 0);
        }
        __builtin_amdgcn_s_setprio(0);
        // causal mask (s > q), per group; fully-masked group -> p=exp(-1e30-m)=0
        if (s0 + 31 > wrow0) {  // diagonal region touches group 0
          const int qrow = wrow0 + lq;
#pragma unroll
          for (int r = 0; r < 4; ++r) {
            if (s0 + quad * 4 + r > qrow) sa00[r] = -1e30f;
            if (s0 + 16 + quad * 4 + r > qrow) sa01[r] = -1e30f;
          }
        }
        if (s0 + 15 > wrow0) {  // diagonal region touches group 1
          const int qrow = wrow0 + 16 + lq;
#pragma unroll
          for (int r = 0; r < 4; ++r) {
            if (s0 + quad * 4 + r > qrow) sa10[r] = -1e30f;
            if (s0 + 16 + quad * 4 + r > qrow) sa11[r] = -1e30f;
          }
        }
        // ---- group 0 softmax ----
        float mx0 = fmaxf(fmaxf(fmaxf(sa00[0], sa00[1]), fmaxf(sa00[2], sa00[3])),
                          fmaxf(fmaxf(sa01[0], sa01[1]), fmaxf(sa01[2], sa01[3])));
        mx0 = fmaxf(mx0, __shfl_xor(mx0, 16));
        mx0 = fmaxf(mx0, __shfl_xor(mx0, 32));
        if (!__all(mx0 - m0 <= 8.f)) {
          const float mnew = fmaxf(m0, mx0);
          const float a = __expf(m0 - mnew);
          li0 *= a;
          m0 = mnew;
#pragma unroll
          for (int r = 0; r < 4; ++r) {
            const float ar = __shfl(a, quad * 4 + r);
#pragma unroll
            for (int ntl = 0; ntl < 16; ++ntl) O0[ntl][r] *= ar;
          }
        }
        const float g0p0 = __expf(sa00[0] - m0), g0p1 = __expf(sa00[1] - m0);
        const float g0p2 = __expf(sa00[2] - m0), g0p3 = __expf(sa00[3] - m0);
        const float g0p4 = __expf(sa01[0] - m0), g0p5 = __expf(sa01[1] - m0);
        const float g0p6 = __expf(sa01[2] - m0), g0p7 = __expf(sa01[3] - m0);
        {
          float rs = ((g0p0 + g0p1) + (g0p2 + g0p3)) + ((g0p4 + g0p5) + (g0p6 + g0p7));
          rs += __shfl_xor(rs, 16);
          rs += __shfl_xor(rs, 32);
          li0 += rs;
        }
        // ---- group 1 softmax ----
        float mx1 = fmaxf(fmaxf(fmaxf(sa10[0], sa10[1]), fmaxf(sa10[2], sa10[3])),
                          fmaxf(fmaxf(sa11[0], sa11[1]), fmaxf(sa11[2], sa11[3])));
        mx1 = fmaxf(mx1, __shfl_xor(mx1, 16));
        mx1 = fmaxf(mx1, __shfl_xor(mx1, 32));
        if (!__all(mx1 - m1 <= 8.f)) {
          const float mnew = fmaxf(m1, mx1);
          const float a = __expf(m1 - mnew);
          li1 *= a;
          m1 = mnew;
#pragma unroll
          for (int r = 0; r < 4; ++r) {
            const float ar = __shfl(a, quad * 4 + r);
#pragma unroll
            for (int ntl = 0; ntl < 16; ++ntl) O1[ntl][r] *= ar;
          }
        }
        const float g1p0 = __expf(sa10[0] - m1), g1p1 = __expf(sa10[1] - m1);
        const float g1p2 = __expf(sa10[2] - m1), g1p3 = __expf(sa10[3] - m1);
        const float g1p4 = __expf(sa11[0] - m1), g1p5 = __expf(sa11[1] - m1);
        const float g1p6 = __expf(sa11[2] - m1), g1p7 = __expf(sa11[3] - m1);
        {
          float rs = ((g1p0 + g1p1) + (g1p2 + g1p3)) + ((g1p4 + g1p5) + (g1p6 + g1p7));
          rs += __shfl_xor(rs, 16);
          rs += __shfl_xor(rs, 32);
          li1 += rs;
        }
        // ---- P exchange (proven select-network), per group ----
        short8 pf0, pf1;
        {
          const uint32 a0 = pkbf(g0p0, g0p1), a1 = pkbf(g0p2, g0p3);
          const uint32 b0 = pkbf(g0p4, g0p5), b1 = pkbf(g0p6, g0p7);
          const uint32 s10 = (quad < 2) ? b0 : a0;
          const uint32 s11 = (quad < 2) ? b1 : a1;
          const uint32 r10 = __shfl_xor(s10, 32);
          const uint32 r11 = __shfl_xor(s11, 32);
          const bool sR = (quad == 0) || (quad == 3);
          const uint32 s20 = sR ? r10 : ((quad == 1) ? a0 : b0);
          const uint32 s21 = sR ? r11 : ((quad == 1) ? a1 : b1);
          const uint32 r20 = __shfl_xor(s20, 16);
          const uint32 r21 = __shfl_xor(s21, 16);
          const uint32 w0 = (quad == 0) ? a0 : (quad == 2) ? r10 : r20;
          const uint32 w1 = (quad == 0) ? a1 : (quad == 2) ? r11 : r21;
          const uint32 w2 = (quad == 1) ? r10 : (quad == 3) ? b0 : r20;
          const uint32 w3 = (quad == 1) ? r11 : (quad == 3) ? b1 : r21;
          const u32x4 pw = (u32x4){w0, w1, w2, w3};
          pf0 = __builtin_bit_cast(short8, pw);
        }
        {
          const uint32 a0 = pkbf(g1p0, g1p1), a1 = pkbf(g1p2, g1p3);
          const uint32 b0 = pkbf(g1p4, g1p5), b1 = pkbf(g1p6, g1p7);
          const uint32 s10 = (quad < 2) ? b0 : a0;
          const uint32 s11 = (quad < 2) ? b1 : a1;
          const uint32 r10 = __shfl_xor(s10, 32);
          const uint32 r11 = __shfl_xor(s11, 32);
          const bool sR = (quad == 0) || (quad == 3);
          const uint32 s20 = sR ? r10 : ((quad == 1) ? a0 : b0);
          const uint32 s21 = sR ? r11 : ((quad == 1) ? a1 : b1);
          const uint32 r20 = __shfl_xor(s20, 16);
          const uint32 r21 = __shfl_xor(s21, 16);
          const uint32 w0 = (quad == 0) ? a0 : (quad == 2) ? r10 : r20;
          const uint32 w1 = (quad == 0) ? a1 : (quad == 2) ? r11 : r21;
          const uint32 w2 = (quad == 1) ? r10 : (quad == 3) ? b0 : r20;
          const uint32 w3 = (quad == 1) ? r11 : (quad == 3) ? b1 : r21;
          const u32x4 pw = (u32x4){w0, w1, w2, w3};
          pf1 = __builtin_bit_cast(short8, pw);
        }
        // ---- PV: each V fragment feeds both groups ----
        const u16* Vc = &VsB[cur][vlx];
        __builtin_amdgcn_s_setprio(1);
#pragma unroll
        for (int ntl = 0; ntl < 16; ++ntl) {
          short8 vf = *(const short8*)&Vc[ntl * 512];
          O0[ntl] = __builtin_amdgcn_mfma_f32_16x16x32_bf16(pf0, vf, O0[ntl], 0, 0, 0);
          O1[ntl] = __builtin_amdgcn_mfma_f32_16x16x32_bf16(pf1, vf, O1[ntl], 0, 0, 0);
        }
        __builtin_amdgcn_s_setprio(0);
      }
      __builtin_amdgcn_s_barrier();  // reads done before next-iter overwrite
      cur ^= 1;
    }
    // epilogue: normalize, store encoded bf16 for both groups
    {
      const float inv = 1.0f / li0;
      float invq[4];
#pragma unroll
      for (int r = 0; r < 4; ++r) invq[r] = __shfl(inv, quad * 4 + r);
      u16* ebase =
          Eb + (((size_t)b * T_SEQ + wrow0 + quad * 4) * N_HEADS + n) * HDIM + lq;
#pragma unroll
      for (int ntl = 0; ntl < 16; ++ntl)
#pragma unroll
        for (int r = 0; r < 4; ++r)
          ebase[(size_t)r * (N_HEADS * HDIM) + ntl * 16] = f2bf(O0[ntl][r] * invq[r]);
    }
    {
      const float inv = 1.0f / li1;
      float invq[4];
#pragma unroll
      for (int r = 0; r < 4; ++r) invq[r] = __shfl(inv, quad * 4 + r);
      u16* ebase =
          Eb + (((size_t)b * T_SEQ + wrow0 + 16 + quad * 4) * N_HEADS + n) * HDIM + lq;
#pragma unroll
      for (int ntl = 0; ntl < 16; ++ntl)
#pragma unroll
        for (int r = 0; r < 4; ++r)
          ebase[(size_t)r * (N_HEADS * HDIM) + ntl * 16] = f2bf(O1[ntl][r] * invq[r]);
    }
  }
}

// ---------------------------------------------------------------------------
// MFMA GEMM 2: out[8192x2048 f32] = Eb(bf16) @ Owt^T.
// Round 8: XCD-aware bijective block swizzle (T1).
// ---------------------------------------------------------------------------
__global__ __launch_bounds__(256) void gemm_out_mfma(const u16* __restrict__ E,
                                                     const u16* __restrict__ Owt,
                                                     float* __restrict__ out) {
  __shared__ u16 Asm[128][32];
  __shared__ u16 Bsm[128][32];
  const int t = threadIdx.x;
  const int w = t >> 6, l = t & 63, quad = l >> 4, lq = l & 15;
  const int wm = w & 1, wn = w >> 1;
  // XCD swizzle: nwg = 16*64 = 1024 (%8==0 -> bijective).
  const int lb = blockIdx.x + 16 * blockIdx.y;
  const int sw = (lb & 7) * 128 + (lb >> 3);
  const int col0 = (sw % 16) * 128, row0 = (sw / 16) * 128;
  const u16* ga0 = E + (size_t)(row0 + (t >> 2)) * D_MODEL + (t & 3) * 8;
  const u16* ga1 = ga0 + (size_t)64 * D_MODEL;
  const u16* gb0 = Owt + (size_t)(col0 + (t >> 2)) * D_MODEL + (t & 3) * 8;
  const u16* gb1 = gb0 + (size_t)64 * D_MODEL;
  u16* lA0 = &Asm[0][0] + t * 8;
  u16* lA1 = lA0 + 2048;
  u16* lB0 = &Bsm[0][0] + t * 8;
  u16* lB1 = lB0 + 2048;
  f32x4 acc[4][4];
#pragma unroll
  for (int i = 0; i < 4; ++i)
#pragma unroll
    for (int j = 0; j < 4; ++j) acc[i][j] = (f32x4){0.f, 0.f, 0.f, 0.f};
  for (int k0 = 0; k0 < D_MODEL; k0 += 32) {
    gload16(ga0 + k0, lA0);
    gload16(ga1 + k0, lA1);
    gload16(gb0 + k0, lB0);
    gload16(gb1 + k0, lB1);
    __syncthreads();
    short8 af[4], bf[4];
#pragma unroll
    for (int i = 0; i < 4; ++i)
      af[i] = *(const short8*)&Asm[wm * 64 + i * 16 + lq][quad * 8];
#pragma unroll
    for (int j = 0; j < 4; ++j)
      bf[j] = *(const short8*)&Bsm[wn * 64 + j * 16 + lq][quad * 8];
#pragma unroll
    for (int i = 0; i < 4; ++i)
#pragma unroll
      for (int j = 0; j < 4; ++j)
        acc[i][j] =
            __builtin_amdgcn_mfma_f32_16x16x32_bf16(af[i], bf[j], acc[i][j], 0, 0, 0);
    __syncthreads();
  }
#pragma unroll
  for (int i = 0; i < 4; ++i) {
    const int row = row0 + wm * 64 + i * 16 + quad * 4;
#pragma unroll
    for (int j = 0; j < 4; ++j) {
      const int col = col0 + wn * 64 + j * 16 + lq;
#pragma unroll
      for (int r = 0; r < 4; ++r)
        out[(size_t)(row + r) * D_MODEL + col] = acc[i][j][r];
    }
  }
}

// ---------------------------------------------------------------------------
extern "C" void kernel_launch(void* const* d_in, const int* in_sizes, int n_in,
                              void* d_out, int out_size, void* d_ws,
                              size_t ws_size, hipStream_t stream) {
  const float* x = (const float*)d_in[0];
  const int* segpos = (const int*)d_in[1];
  // d_in[2] = attn_mask (causal tril) — analytic, not read.
  const float* qw = (const float*)d_in[3];
  const float* kvw = (const float*)d_in[4];
  const float* ow = (const float*)d_in[5];
  float* out = (float*)d_out;

  char* ws = (char*)d_ws;
  u16* Qb = (u16*)ws;                                    // 32 MiB
  u16* Kb = (u16*)(ws + (size_t)33554432);               // 4 MiB
  u16* Vt = (u16*)(ws + (size_t)37748736);               // 4 MiB (transposed)
  u16* xb = (u16*)(ws + (size_t)41943040);               // 32 MiB (aliases Eb)
  u16* Eb = xb;  // xb dead after gemm_qkv_mfma
  u16* Wt = (u16*)(ws + (size_t)75497472);               // 10 MiB
  u16* Owt = (u16*)(ws + (size_t)85983232);              // 8 MiB  (total 90 MiB)

  hipLaunchKernelGGL(convert_x, dim3(16384), dim3(256), 0, stream, x, xb);
  hipLaunchKernelGGL(prep_weights, dim3(40, 32, 2), dim3(256), 0, stream, qw,
                     kvw, ow, Wt, Owt);
  hipLaunchKernelGGL(gemm_qkv_mfma, dim3(20, 64), dim3(256), 0, stream, xb, Wt,
                     Qb, Kb, Vt);
  hipLaunchKernelGGL(rope_kernel, dim3(8192), dim3(256), 0, stream, Qb, Kb,
                     segpos);
  hipLaunchKernelGGL(attn_mfma, dim3(16, N_HEADS, 2), dim3(256), 0, stream, Qb,
                     Kb, Vt, Eb);
  hipLaunchKernelGGL(gemm_out_mfma, dim3(16, 64), dim3(256), 0, stream, Eb, Owt,
                     out);
}

// Round 9
// 767.959 us; speedup vs baseline: 1.0206x; 1.0206x over previous
//
#include <hip/hip_runtime.h>

// Problem constants: B=2, T=4096, D=2048, N=8 heads, K=1 kv-head, H=256
#define T_SEQ 4096
#define D_MODEL 2048
#define N_HEADS 8
#define HDIM 256

typedef unsigned int uint32;
typedef unsigned short u16;
typedef __attribute__((ext_vector_type(8))) short short8;  // 8 bf16 (4 VGPRs)
typedef __attribute__((ext_vector_type(4))) float f32x4;
typedef __attribute__((ext_vector_type(4))) uint32 u32x4;

__device__ __forceinline__ float bf2f(u16 v) {
  return __uint_as_float(((uint32)v) << 16);
}
__device__ __forceinline__ u16 f2bf(float f) {
  uint32 u = __float_as_uint(f);
  u += 0x7fffu + ((u >> 16) & 1u);  // round-to-nearest-even
  return (u16)(u >> 16);
}
__device__ __forceinline__ uint32 pkbf(float x, float y) {
  return (uint32)f2bf(x) | ((uint32)f2bf(y) << 16);
}
__device__ __forceinline__ uint2 pack4(const f32x4 v) {
  uint2 r;
  r.x = (uint32)f2bf(v[0]) | ((uint32)f2bf(v[1]) << 16);
  r.y = (uint32)f2bf(v[2]) | ((uint32)f2bf(v[3]) << 16);
  return r;
}
// async global->LDS, 16B per lane; LDS dest must be lane-contiguous.
__device__ __forceinline__ void gload16(const u16* g, u16* l) {
  __builtin_amdgcn_global_load_lds(
      (const __attribute__((address_space(1))) unsigned int*)g,
      (__attribute__((address_space(3))) unsigned int*)l, 16, 0, 0);
}

// ---------------------------------------------------------------------------
// Prep 1: x (f32) -> xb (bf16), row-major [8192][2048].
// ---------------------------------------------------------------------------
__global__ __launch_bounds__(256) void convert_x(const float* __restrict__ x,
                                                 u16* __restrict__ xb) {
  const int idx = blockIdx.x * 256 + threadIdx.x;  // 4 elems each
  float4 v = *(const float4*)(x + (size_t)idx * 4);
  uint2 pk;
  pk.x = (uint32)f2bf(v.x) | ((uint32)f2bf(v.y) << 16);
  pk.y = (uint32)f2bf(v.z) | ((uint32)f2bf(v.w) << 16);
  *(uint2*)(xb + (size_t)idx * 4) = pk;
}

// ---------------------------------------------------------------------------
// Prep 2: transpose+convert weights to bf16 B^T layouts:
//   z=0: W_all[d][c] (c<2048: qw head c>>8 col c&255; else kv) -> Wt[c][d]
//   z=1: ow[k][d] (k = n*256+h)                                -> Owt[d][k]
// ---------------------------------------------------------------------------
__global__ __launch_bounds__(256) void prep_weights(
    const float* __restrict__ qw, const float* __restrict__ kvw,
    const float* __restrict__ ow, u16* __restrict__ Wt, u16* __restrict__ Owt) {
  __shared__ float Ts[64][65];
  const int t = threadIdx.x;
  const int tx = blockIdx.x, ty = blockIdx.y, z = blockIdx.z;
  const float* src;
  int srcStride;
  u16* dst;
  if (z == 0) {
    const int c0 = tx * 64;
    const float* base = (c0 < 2048)
                            ? qw + (size_t)(c0 >> 8) * D_MODEL * HDIM
                            : kvw + (size_t)((c0 - 2048) >> 8) * D_MODEL * HDIM;
    src = base + (c0 & 255);
    srcStride = HDIM;
    dst = Wt + (size_t)c0 * D_MODEL;
  } else {
    if (tx >= 32) return;
    src = ow + tx * 64;
    srcStride = D_MODEL;
    dst = Owt + (size_t)tx * 64 * D_MODEL;
  }
  const int d0 = ty * 64;
  const int r = t >> 4, c4 = (t & 15) * 4;
#pragma unroll
  for (int i = 0; i < 4; ++i) {
    float4 v = *(const float4*)(src + (size_t)(d0 + r + i * 16) * srcStride + c4);
    *(float4*)&Ts[r + i * 16][c4] = v;
  }
  __syncthreads();
#pragma unroll
  for (int i = 0; i < 4; ++i) {
    const int crow = r + i * 16;  // output row (source col)
    uint2 pk;
    pk.x = (uint32)f2bf(Ts[c4 + 0][crow]) | ((uint32)f2bf(Ts[c4 + 1][crow]) << 16);
    pk.y = (uint32)f2bf(Ts[c4 + 2][crow]) | ((uint32)f2bf(Ts[c4 + 3][crow]) << 16);
    *(uint2*)(dst + (size_t)crow * D_MODEL + d0 + c4) = pk;
  }
}

// ---------------------------------------------------------------------------
// MFMA GEMM 1: [xb 8192x2048 bf16] @ [Wt^T] -> Q/K/V.  cols: 0..2047 Q,
// 2048..2303 K, 2304..2559 V (written transposed Vt[b][h][s]).
// XCD-aware bijective block swizzle (T1) for L2 panel reuse.
// ---------------------------------------------------------------------------
__global__ __launch_bounds__(256) void gemm_qkv_mfma(
    const u16* __restrict__ xb, const u16* __restrict__ Wt,
    u16* __restrict__ Qb, u16* __restrict__ Kb, u16* __restrict__ Vt) {
  __shared__ u16 Asm[128][32];
  __shared__ u16 Bsm[128][32];
  const int t = threadIdx.x;
  const int w = t >> 6, l = t & 63, quad = l >> 4, lq = l & 15;
  const int wm = w & 1, wn = w >> 1;
  // XCD swizzle: nwg = 20*64 = 1280 (%8==0 -> bijective).
  const int lb = blockIdx.x + 20 * blockIdx.y;
  const int sw = (lb & 7) * 160 + (lb >> 3);
  const int col0 = (sw % 20) * 128, row0 = (sw / 20) * 128;
  const u16* ga0 = xb + (size_t)(row0 + (t >> 2)) * D_MODEL + (t & 3) * 8;
  const u16* ga1 = ga0 + (size_t)64 * D_MODEL;
  const u16* gb0 = Wt + (size_t)(col0 + (t >> 2)) * D_MODEL + (t & 3) * 8;
  const u16* gb1 = gb0 + (size_t)64 * D_MODEL;
  u16* lA0 = &Asm[0][0] + t * 8;
  u16* lA1 = lA0 + 2048;
  u16* lB0 = &Bsm[0][0] + t * 8;
  u16* lB1 = lB0 + 2048;
  f32x4 acc[4][4];
#pragma unroll
  for (int i = 0; i < 4; ++i)
#pragma unroll
    for (int j = 0; j < 4; ++j) acc[i][j] = (f32x4){0.f, 0.f, 0.f, 0.f};
  for (int k0 = 0; k0 < D_MODEL; k0 += 32) {
    gload16(ga0 + k0, lA0);
    gload16(ga1 + k0, lA1);
    gload16(gb0 + k0, lB0);
    gload16(gb1 + k0, lB1);
    __syncthreads();
    short8 af[4], bf[4];
#pragma unroll
    for (int i = 0; i < 4; ++i)
      af[i] = *(const short8*)&Asm[wm * 64 + i * 16 + lq][quad * 8];
#pragma unroll
    for (int j = 0; j < 4; ++j)
      bf[j] = *(const short8*)&Bsm[wn * 64 + j * 16 + lq][quad * 8];
#pragma unroll
    for (int i = 0; i < 4; ++i)
#pragma unroll
      for (int j = 0; j < 4; ++j)
        acc[i][j] =
            __builtin_amdgcn_mfma_f32_16x16x32_bf16(af[i], bf[j], acc[i][j], 0, 0, 0);
    __syncthreads();
  }
  const int b = row0 >> 12, sbase = row0 & 4095;
#pragma unroll
  for (int i = 0; i < 4; ++i) {
    const int rowloc = wm * 64 + i * 16 + quad * 4;
#pragma unroll
    for (int j = 0; j < 4; ++j) {
      const int col = col0 + wn * 64 + j * 16 + lq;
      if (col < 2048) {
#pragma unroll
        for (int r = 0; r < 4; ++r)
          Qb[(size_t)(row0 + rowloc + r) * 2048 + col] = f2bf(acc[i][j][r]);
      } else if (col < 2304) {
#pragma unroll
        for (int r = 0; r < 4; ++r)
          Kb[(size_t)(row0 + rowloc + r) * HDIM + (col - 2048)] =
              f2bf(acc[i][j][r]);
      } else {
        *(uint2*)(Vt + ((size_t)b * HDIM + col - 2304) * T_SEQ + sbase + rowloc) =
            pack4(acc[i][j]);
      }
    }
  }
}

// ---------------------------------------------------------------------------
// RoPE (in-place on bf16 Q and K) + query scaling by H^-0.5.
// ---------------------------------------------------------------------------
__global__ __launch_bounds__(256) void rope_kernel(u16* __restrict__ Qb,
                                                   u16* __restrict__ Kb,
                                                   const int* __restrict__ segpos) {
  const int bt = blockIdx.x;
  const int tid = threadIdx.x;
  const float fpos = (float)segpos[bt];
  const float k_ln = 9.210340371976184f / 128.0f;  // ln(10000)/(H/2)
  for (int p = tid; p < 1024; p += 256) {
    const int n = p >> 7, i = p & 127;
    const size_t base = (size_t)bt * (N_HEADS * HDIM) + (size_t)n * HDIM;
    const float th = fpos * expf(-(float)i * k_ln);
    float s, c;
    sincosf(th, &s, &c);
    const float f1 = bf2f(Qb[base + i]);
    const float f2 = bf2f(Qb[base + i + 128]);
    Qb[base + i] = f2bf((f1 * c - f2 * s) * 0.0625f);
    Qb[base + i + 128] = f2bf((f2 * c + f1 * s) * 0.0625f);
  }
  if (tid < 128) {
    const int i = tid;
    const size_t base = (size_t)bt * HDIM;
    const float th = fpos * expf(-(float)i * k_ln);
    float s, c;
    sincosf(th, &s, &c);
    const float f1 = bf2f(Kb[base + i]);
    const float f2 = bf2f(Kb[base + i + 128]);
    Kb[base + i] = f2bf(f1 * c - f2 * s);
    Kb[base + i + 128] = f2bf(f2 * c + f1 * s);
  }
}

// ---------------------------------------------------------------------------
// MFMA flash attention (causal, MQA) — Round 9: 32q/wave + restored occupancy.
// R8 post-mortem: 32q/wave halved LDS traffic (conflicts 1.69e7->8.45e6) but
// grid 256 blocks = 1 block/CU = 1 wave/SIMD (Occupancy 22->11.8%) -> every
// latency exposed, net regression. Fix: ONE 128-row q-tile per block, grid
// (32, 8, 2) = 512 blocks; LDS 64KB/block and VGPR<=256 (launch_bounds
// (256,2)) -> exactly 2 blocks/CU = 2 waves/SIMD, same as the 265us R6
// config, with half the LDS traffic per unit work. Load balance without the
// ti-loop: qt = (z==0) ? 31-bid : bid — blocks i and i+256 (same x,y) land
// on the same CU under both plausible wgid->CU mappings and their work sums
// to the constant 132 iters.
// Kernel-internal structure identical to R8 (swapped QK^T, K/V chunk-XOR
// swizzles, gload_lds dbuf, counted vmcnt(8), shfl_xor select-network P
// exchange, defer-max, setprio).
// ---------------------------------------------------------------------------
__global__ __launch_bounds__(256, 2) void attn_mfma(const u16* __restrict__ Qb,
                                                    const u16* __restrict__ Kb,
                                                    const u16* __restrict__ Vt,
                                                    u16* __restrict__ Eb) {
  __shared__ u16 KsB[2][8192];  // [buf] 32 s-rows x 256 h (16B chunks swizzled)
  __shared__ u16 VsB[2][8192];  // [buf] 256 h-rows x 32 s (16B chunks swizzled)
  const int t = threadIdx.x;
  const int w = t >> 6, l = t & 63;
  const int quad = l >> 4, lq = l & 15;
  const int sx = lq & 7;
  const int bid = blockIdx.x;  // 0..31
  const int n = blockIdx.y, b = blockIdx.z;
  const u16* kgbase = Kb + (size_t)b * T_SEQ * HDIM;
  const u16* vgbase = Vt + (size_t)b * HDIM * T_SEQ;

  // Per-thread staging geometry: 4 K-chunks + 4 V-chunks of 16B per s-tile.
  // LDS is written linearly (wave-uniform base + lane*16); both K and V
  // carry their inverse swizzle on the global source address.
  int koff[4], voff[4], ldo[4];
#pragma unroll
  for (int p = 0; p < 4; ++p) {
    const int cid = w * 4 + p;              // 16 chunks of 1KB per 16KB tile
    const int krow = 2 * cid + (l >> 5);    // K row 0..31
    const int kchk = (l & 31) ^ (krow & 7); // swizzled 16B chunk within row
    koff[p] = krow * HDIM + kchk * 8;
    const int s_ = cid * 64 + l;            // physical 16B chunk 0..1023
    const int c_ = s_ ^ ((s_ >> 3) & 7);    // logical chunk (involution)
    voff[p] = (c_ >> 2) * T_SEQ + (c_ & 3) * 8;  // V h-row, s-chunk
    ldo[p] = cid * 512 + l * 8;             // u16 offset inside 16KB buffer
  }
  // V read-side swizzled per-lane offset (constant across ntl/iter):
  const int vlx = (lq * 32 + quad * 8) ^ ((lq >> 1) << 3);

  auto stage = [&](int buf, int s0) {
#pragma unroll
    for (int p = 0; p < 4; ++p)
      gload16(kgbase + (size_t)s0 * HDIM + koff[p], &KsB[buf][ldo[p]]);
#pragma unroll
    for (int p = 0; p < 4; ++p)
      gload16(vgbase + (size_t)voff[p] + s0, &VsB[buf][ldo[p]]);
  };

  // Complementary CU pairing: blocks (x,y,0) and (x,y,1) likely co-resident;
  // their iteration counts sum to 132.
  const int qt = (b == 0) ? (31 - bid) : bid;
  const int q0 = qt * 128;
  const int wrow0 = q0 + w * 32;  // this wave: q-rows wrow0..wrow0+31

  // Q fragments for both 16-row groups (8 chunks of K=32 head-dims each).
  short8 qf0[8], qf1[8];
  {
    const u16* qb0 = Qb +
        (((size_t)b * T_SEQ + wrow0 + lq) * N_HEADS + n) * HDIM + quad * 8;
    const u16* qb1 = qb0 + (size_t)16 * N_HEADS * HDIM;
#pragma unroll
    for (int c = 0; c < 8; ++c) {
      qf0[c] = *(const short8*)(qb0 + c * 32);
      qf1[c] = *(const short8*)(qb1 + c * 32);
    }
  }
  stage(0, 0);

  f32x4 O0[16], O1[16];
#pragma unroll
  for (int i = 0; i < 16; ++i) {
    O0[i] = (f32x4){0.f, 0.f, 0.f, 0.f};
    O1[i] = (f32x4){0.f, 0.f, 0.f, 0.f};
  }
  float m0 = -1e30f, li0 = 0.f;
  float m1 = -1e30f, li1 = 0.f;

  const int nst = 4 * qt + 4;
  int cur = 0;
#pragma unroll 1
  for (int st = 0; st < nst; ++st) {
    const int s0 = st * 32;
    if (st + 1 < nst) {
      stage(cur ^ 1, s0 + 32);
      // current tile's 8 loads are the 8-before-last -> counted wait keeps
      // the prefetch in flight across the barrier.
      asm volatile("s_waitcnt vmcnt(8)" ::: "memory");
    } else {
      asm volatile("s_waitcnt vmcnt(0)" ::: "memory");
    }
    __builtin_amdgcn_s_barrier();
    if (s0 <= wrow0 + 31) {  // wave-uniform skip (both groups fully masked)
      const u16* Kc = &KsB[cur][0];
      f32x4 sa00 = (f32x4){0.f, 0.f, 0.f, 0.f};
      f32x4 sa01 = (f32x4){0.f, 0.f, 0.f, 0.f};
      f32x4 sa10 = (f32x4){0.f, 0.f, 0.f, 0.f};
      f32x4 sa11 = (f32x4){0.f, 0.f, 0.f, 0.f};
      __builtin_amdgcn_s_setprio(1);
#pragma unroll
      for (int c = 0; c < 8; ++c) {
        const int cb = ((c * 4 + quad) ^ sx) * 8;
        short8 k0 = *(const short8*)&Kc[lq * 256 + cb];
        short8 k1 = *(const short8*)&Kc[(16 + lq) * 256 + cb];
        // swapped operands: lane holds S[q=group row lq][s=quad*4+r (+16)]
        sa00 = __builtin_amdgcn_mfma_f32_16x16x32_bf16(k0, qf0[c], sa00, 0, 0, 0);
        sa01 = __builtin_amdgcn_mfma_f32_16x16x32_bf16(k1, qf0[c], sa01, 0, 0, 0);
        sa10 = __builtin_amdgcn_mfma_f32_16x16x32_bf16(k0, qf1[c], sa10, 0, 0, 0);
        sa11 = __builtin_amdgcn_mfma_f32_16x16x32_bf16(k1, qf1[c], sa11, 0, 0, 0);
      }
      __builtin_amdgcn_s_setprio(0);
      // causal mask (s > q), per group; fully-masked group -> p=0 via exp
      if (s0 + 31 > wrow0) {  // diagonal region touches group 0
        const int qrow = wrow0 + lq;
#pragma unroll
        for (int r = 0; r < 4; ++r) {
          if (s0 + quad * 4 + r > qrow) sa00[r] = -1e30f;
          if (s0 + 16 + quad * 4 + r > qrow) sa01[r] = -1e30f;
        }
      }
      if (s0 + 15 > wrow0) {  // diagonal region touches group 1
        const int qrow = wrow0 + 16 + lq;
#pragma unroll
        for (int r = 0; r < 4; ++r) {
          if (s0 + quad * 4 + r > qrow) sa10[r] = -1e30f;
          if (s0 + 16 + quad * 4 + r > qrow) sa11[r] = -1e30f;
        }
      }
      // ---- group 0 softmax ----
      float mx0 = fmaxf(fmaxf(fmaxf(sa00[0], sa00[1]), fmaxf(sa00[2], sa00[3])),
                        fmaxf(fmaxf(sa01[0], sa01[1]), fmaxf(sa01[2], sa01[3])));
      mx0 = fmaxf(mx0, __shfl_xor(mx0, 16));
      mx0 = fmaxf(mx0, __shfl_xor(mx0, 32));
      if (!__all(mx0 - m0 <= 8.f)) {
        const float mnew = fmaxf(m0, mx0);
        const float a = __expf(m0 - mnew);
        li0 *= a;
        m0 = mnew;
#pragma unroll
        for (int r = 0; r < 4; ++r) {
          const float ar = __shfl(a, quad * 4 + r);
#pragma unroll
          for (int ntl = 0; ntl < 16; ++ntl) O0[ntl][r] *= ar;
        }
      }
      const float g0p0 = __expf(sa00[0] - m0), g0p1 = __expf(sa00[1] - m0);
      const float g0p2 = __expf(sa00[2] - m0), g0p3 = __expf(sa00[3] - m0);
      const float g0p4 = __expf(sa01[0] - m0), g0p5 = __expf(sa01[1] - m0);
      const float g0p6 = __expf(sa01[2] - m0), g0p7 = __expf(sa01[3] - m0);
      {
        float rs = ((g0p0 + g0p1) + (g0p2 + g0p3)) + ((g0p4 + g0p5) + (g0p6 + g0p7));
        rs += __shfl_xor(rs, 16);
        rs += __shfl_xor(rs, 32);
        li0 += rs;
      }
      // ---- group 1 softmax ----
      float mx1 = fmaxf(fmaxf(fmaxf(sa10[0], sa10[1]), fmaxf(sa10[2], sa10[3])),
                        fmaxf(fmaxf(sa11[0], sa11[1]), fmaxf(sa11[2], sa11[3])));
      mx1 = fmaxf(mx1, __shfl_xor(mx1, 16));
      mx1 = fmaxf(mx1, __shfl_xor(mx1, 32));
      if (!__all(mx1 - m1 <= 8.f)) {
        const float mnew = fmaxf(m1, mx1);
        const float a = __expf(m1 - mnew);
        li1 *= a;
        m1 = mnew;
#pragma unroll
        for (int r = 0; r < 4; ++r) {
          const float ar = __shfl(a, quad * 4 + r);
#pragma unroll
          for (int ntl = 0; ntl < 16; ++ntl) O1[ntl][r] *= ar;
        }
      }
      const float g1p0 = __expf(sa10[0] - m1), g1p1 = __expf(sa10[1] - m1);
      const float g1p2 = __expf(sa10[2] - m1), g1p3 = __expf(sa10[3] - m1);
      const float g1p4 = __expf(sa11[0] - m1), g1p5 = __expf(sa11[1] - m1);
      const float g1p6 = __expf(sa11[2] - m1), g1p7 = __expf(sa11[3] - m1);
      {
        float rs = ((g1p0 + g1p1) + (g1p2 + g1p3)) + ((g1p4 + g1p5) + (g1p6 + g1p7));
        rs += __shfl_xor(rs, 16);
        rs += __shfl_xor(rs, 32);
        li1 += rs;
      }
      // ---- P exchange (proven select-network), per group ----
      short8 pf0, pf1;
      {
        const uint32 a0 = pkbf(g0p0, g0p1), a1 = pkbf(g0p2, g0p3);
        const uint32 b0 = pkbf(g0p4, g0p5), b1 = pkbf(g0p6, g0p7);
        const uint32 s10 = (quad < 2) ? b0 : a0;
        const uint32 s11 = (quad < 2) ? b1 : a1;
        const uint32 r10 = __shfl_xor(s10, 32);
        const uint32 r11 = __shfl_xor(s11, 32);
        const bool sR = (quad == 0) || (quad == 3);
        const uint32 s20 = sR ? r10 : ((quad == 1) ? a0 : b0);
        const uint32 s21 = sR ? r11 : ((quad == 1) ? a1 : b1);
        const uint32 r20 = __shfl_xor(s20, 16);
        const uint32 r21 = __shfl_xor(s21, 16);
        const uint32 w0 = (quad == 0) ? a0 : (quad == 2) ? r10 : r20;
        const uint32 w1 = (quad == 0) ? a1 : (quad == 2) ? r11 : r21;
        const uint32 w2 = (quad == 1) ? r10 : (quad == 3) ? b0 : r20;
        const uint32 w3 = (quad == 1) ? r11 : (quad == 3) ? b1 : r21;
        const u32x4 pw = (u32x4){w0, w1, w2, w3};
        pf0 = __builtin_bit_cast(short8, pw);
      }
      {
        const uint32 a0 = pkbf(g1p0, g1p1), a1 = pkbf(g1p2, g1p3);
        const uint32 b0 = pkbf(g1p4, g1p5), b1 = pkbf(g1p6, g1p7);
        const uint32 s10 = (quad < 2) ? b0 : a0;
        const uint32 s11 = (quad < 2) ? b1 : a1;
        const uint32 r10 = __shfl_xor(s10, 32);
        const uint32 r11 = __shfl_xor(s11, 32);
        const bool sR = (quad == 0) || (quad == 3);
        const uint32 s20 = sR ? r10 : ((quad == 1) ? a0 : b0);
        const uint32 s21 = sR ? r11 : ((quad == 1) ? a1 : b1);
        const uint32 r20 = __shfl_xor(s20, 16);
        const uint32 r21 = __shfl_xor(s21, 16);
        const uint32 w0 = (quad == 0) ? a0 : (quad == 2) ? r10 : r20;
        const uint32 w1 = (quad == 0) ? a1 : (quad == 2) ? r11 : r21;
        const uint32 w2 = (quad == 1) ? r10 : (quad == 3) ? b0 : r20;
        const uint32 w3 = (quad == 1) ? r11 : (quad == 3) ? b1 : r21;
        const u32x4 pw = (u32x4){w0, w1, w2, w3};
        pf1 = __builtin_bit_cast(short8, pw);
      }
      // ---- PV: each V fragment feeds both groups ----
      const u16* Vc = &VsB[cur][vlx];
      __builtin_amdgcn_s_setprio(1);
#pragma unroll
      for (int ntl = 0; ntl < 16; ++ntl) {
        short8 vf = *(const short8*)&Vc[ntl * 512];
        O0[ntl] = __builtin_amdgcn_mfma_f32_16x16x32_bf16(pf0, vf, O0[ntl], 0, 0, 0);
        O1[ntl] = __builtin_amdgcn_mfma_f32_16x16x32_bf16(pf1, vf, O1[ntl], 0, 0, 0);
      }
      __builtin_amdgcn_s_setprio(0);
    }
    __builtin_amdgcn_s_barrier();  // reads done before next-iter overwrite
    cur ^= 1;
  }
  // epilogue: normalize, store encoded bf16 for both groups
  {
    const float inv = 1.0f / li0;
    float invq[4];
#pragma unroll
    for (int r = 0; r < 4; ++r) invq[r] = __shfl(inv, quad * 4 + r);
    u16* ebase =
        Eb + (((size_t)b * T_SEQ + wrow0 + quad * 4) * N_HEADS + n) * HDIM + lq;
#pragma unroll
    for (int ntl = 0; ntl < 16; ++ntl)
#pragma unroll
      for (int r = 0; r < 4; ++r)
        ebase[(size_t)r * (N_HEADS * HDIM) + ntl * 16] = f2bf(O0[ntl][r] * invq[r]);
  }
  {
    const float inv = 1.0f / li1;
    float invq[4];
#pragma unroll
    for (int r = 0; r < 4; ++r) invq[r] = __shfl(inv, quad * 4 + r);
    u16* ebase =
        Eb + (((size_t)b * T_SEQ + wrow0 + 16 + quad * 4) * N_HEADS + n) * HDIM + lq;
#pragma unroll
    for (int ntl = 0; ntl < 16; ++ntl)
#pragma unroll
      for (int r = 0; r < 4; ++r)
        ebase[(size_t)r * (N_HEADS * HDIM) + ntl * 16] = f2bf(O1[ntl][r] * invq[r]);
  }
}

// ---------------------------------------------------------------------------
// MFMA GEMM 2: out[8192x2048 f32] = Eb(bf16) @ Owt^T.
// XCD-aware bijective block swizzle (T1).
// ---------------------------------------------------------------------------
__global__ __launch_bounds__(256) void gemm_out_mfma(const u16* __restrict__ E,
                                                     const u16* __restrict__ Owt,
                                                     float* __restrict__ out) {
  __shared__ u16 Asm[128][32];
  __shared__ u16 Bsm[128][32];
  const int t = threadIdx.x;
  const int w = t >> 6, l = t & 63, quad = l >> 4, lq = l & 15;
  const int wm = w & 1, wn = w >> 1;
  // XCD swizzle: nwg = 16*64 = 1024 (%8==0 -> bijective).
  const int lb = blockIdx.x + 16 * blockIdx.y;
  const int sw = (lb & 7) * 128 + (lb >> 3);
  const int col0 = (sw % 16) * 128, row0 = (sw / 16) * 128;
  const u16* ga0 = E + (size_t)(row0 + (t >> 2)) * D_MODEL + (t & 3) * 8;
  const u16* ga1 = ga0 + (size_t)64 * D_MODEL;
  const u16* gb0 = Owt + (size_t)(col0 + (t >> 2)) * D_MODEL + (t & 3) * 8;
  const u16* gb1 = gb0 + (size_t)64 * D_MODEL;
  u16* lA0 = &Asm[0][0] + t * 8;
  u16* lA1 = lA0 + 2048;
  u16* lB0 = &Bsm[0][0] + t * 8;
  u16* lB1 = lB0 + 2048;
  f32x4 acc[4][4];
#pragma unroll
  for (int i = 0; i < 4; ++i)
#pragma unroll
    for (int j = 0; j < 4; ++j) acc[i][j] = (f32x4){0.f, 0.f, 0.f, 0.f};
  for (int k0 = 0; k0 < D_MODEL; k0 += 32) {
    gload16(ga0 + k0, lA0);
    gload16(ga1 + k0, lA1);
    gload16(gb0 + k0, lB0);
    gload16(gb1 + k0, lB1);
    __syncthreads();
    short8 af[4], bf[4];
#pragma unroll
    for (int i = 0; i < 4; ++i)
      af[i] = *(const short8*)&Asm[wm * 64 + i * 16 + lq][quad * 8];
#pragma unroll
    for (int j = 0; j < 4; ++j)
      bf[j] = *(const short8*)&Bsm[wn * 64 + j * 16 + lq][quad * 8];
#pragma unroll
    for (int i = 0; i < 4; ++i)
#pragma unroll
      for (int j = 0; j < 4; ++j)
        acc[i][j] =
            __builtin_amdgcn_mfma_f32_16x16x32_bf16(af[i], bf[j], acc[i][j], 0, 0, 0);
    __syncthreads();
  }
#pragma unroll
  for (int i = 0; i < 4; ++i) {
    const int row = row0 + wm * 64 + i * 16 + quad * 4;
#pragma unroll
    for (int j = 0; j < 4; ++j) {
      const int col = col0 + wn * 64 + j * 16 + lq;
#pragma unroll
      for (int r = 0; r < 4; ++r)
        out[(size_t)(row + r) * D_MODEL + col] = acc[i][j][r];
    }
  }
}

// ---------------------------------------------------------------------------
extern "C" void kernel_launch(void* const* d_in, const int* in_sizes, int n_in,
                              void* d_out, int out_size, void* d_ws,
                              size_t ws_size, hipStream_t stream) {
  const float* x = (const float*)d_in[0];
  const int* segpos = (const int*)d_in[1];
  // d_in[2] = attn_mask (causal tril) — analytic, not read.
  const float* qw = (const float*)d_in[3];
  const float* kvw = (const float*)d_in[4];
  const float* ow = (const float*)d_in[5];
  float* out = (float*)d_out;

  char* ws = (char*)d_ws;
  u16* Qb = (u16*)ws;                                    // 32 MiB
  u16* Kb = (u16*)(ws + (size_t)33554432);               // 4 MiB
  u16* Vt = (u16*)(ws + (size_t)37748736);               // 4 MiB (transposed)
  u16* xb = (u16*)(ws + (size_t)41943040);               // 32 MiB (aliases Eb)
  u16* Eb = xb;  // xb dead after gemm_qkv_mfma
  u16* Wt = (u16*)(ws + (size_t)75497472);               // 10 MiB
  u16* Owt = (u16*)(ws + (size_t)85983232);              // 8 MiB  (total 90 MiB)

  hipLaunchKernelGGL(convert_x, dim3(16384), dim3(256), 0, stream, x, xb);
  hipLaunchKernelGGL(prep_weights, dim3(40, 32, 2), dim3(256), 0, stream, qw,
                     kvw, ow, Wt, Owt);
  hipLaunchKernelGGL(gemm_qkv_mfma, dim3(20, 64), dim3(256), 0, stream, xb, Wt,
                     Qb, Kb, Vt);
  hipLaunchKernelGGL(rope_kernel, dim3(8192), dim3(256), 0, stream, Qb, Kb,
                     segpos);
  hipLaunchKernelGGL(attn_mfma, dim3(32, N_HEADS, 2), dim3(256), 0, stream, Qb,
                     Kb, Vt, Eb);
  hipLaunchKernelGGL(gemm_out_mfma, dim3(16, 64), dim3(256), 0, stream, Eb, Owt,
                     out);
}

// Round 11
// 691.875 us; speedup vs baseline: 1.1328x; 1.1100x over previous
//
#include <hip/hip_runtime.h>

// Problem constants: B=2, T=4096, D=2048, N=8 heads, K=1 kv-head, H=256
#define T_SEQ 4096
#define D_MODEL 2048
#define N_HEADS 8
#define HDIM 256

typedef unsigned int uint32;
typedef unsigned short u16;
typedef __attribute__((ext_vector_type(8))) short short8;  // 8 bf16 (4 VGPRs)
typedef __attribute__((ext_vector_type(4))) float f32x4;
typedef __attribute__((ext_vector_type(4))) uint32 u32x4;

__device__ __forceinline__ float bf2f(u16 v) {
  return __uint_as_float(((uint32)v) << 16);
}
__device__ __forceinline__ u16 f2bf(float f) {
  uint32 u = __float_as_uint(f);
  u += 0x7fffu + ((u >> 16) & 1u);  // round-to-nearest-even
  return (u16)(u >> 16);
}
__device__ __forceinline__ uint32 pkbf(float x, float y) {
  return (uint32)f2bf(x) | ((uint32)f2bf(y) << 16);
}
__device__ __forceinline__ uint2 pack4(const f32x4 v) {
  uint2 r;
  r.x = (uint32)f2bf(v[0]) | ((uint32)f2bf(v[1]) << 16);
  r.y = (uint32)f2bf(v[2]) | ((uint32)f2bf(v[3]) << 16);
  return r;
}
// async global->LDS, 16B per lane; LDS dest must be lane-contiguous.
__device__ __forceinline__ void gload16(const u16* g, u16* l) {
  __builtin_amdgcn_global_load_lds(
      (const __attribute__((address_space(1))) unsigned int*)g,
      (__attribute__((address_space(3))) unsigned int*)l, 16, 0, 0);
}

// ---------------------------------------------------------------------------
// Prep 1: x (f32) -> xb (bf16), row-major [8192][2048].
// ---------------------------------------------------------------------------
__global__ __launch_bounds__(256) void convert_x(const float* __restrict__ x,
                                                 u16* __restrict__ xb) {
  const int idx = blockIdx.x * 256 + threadIdx.x;  // 4 elems each
  float4 v = *(const float4*)(x + (size_t)idx * 4);
  uint2 pk;
  pk.x = (uint32)f2bf(v.x) | ((uint32)f2bf(v.y) << 16);
  pk.y = (uint32)f2bf(v.z) | ((uint32)f2bf(v.w) << 16);
  *(uint2*)(xb + (size_t)idx * 4) = pk;
}

// ---------------------------------------------------------------------------
// Prep 2: transpose+convert weights to bf16 B^T layouts:
//   z=0: W_all[d][c] (c<2048: qw head c>>8 col c&255; else kv) -> Wt[c][d]
//   z=1: ow[k][d] (k = n*256+h)                                -> Owt[d][k]
// ---------------------------------------------------------------------------
__global__ __launch_bounds__(256) void prep_weights(
    const float* __restrict__ qw, const float* __restrict__ kvw,
    const float* __restrict__ ow, u16* __restrict__ Wt, u16* __restrict__ Owt) {
  __shared__ float Ts[64][65];
  const int t = threadIdx.x;
  const int tx = blockIdx.x, ty = blockIdx.y, z = blockIdx.z;
  const float* src;
  int srcStride;
  u16* dst;
  if (z == 0) {
    const int c0 = tx * 64;
    const float* base = (c0 < 2048)
                            ? qw + (size_t)(c0 >> 8) * D_MODEL * HDIM
                            : kvw + (size_t)((c0 - 2048) >> 8) * D_MODEL * HDIM;
    src = base + (c0 & 255);
    srcStride = HDIM;
    dst = Wt + (size_t)c0 * D_MODEL;
  } else {
    if (tx >= 32) return;
    src = ow + tx * 64;
    srcStride = D_MODEL;
    dst = Owt + (size_t)tx * 64 * D_MODEL;
  }
  const int d0 = ty * 64;
  const int r = t >> 4, c4 = (t & 15) * 4;
#pragma unroll
  for (int i = 0; i < 4; ++i) {
    float4 v = *(const float4*)(src + (size_t)(d0 + r + i * 16) * srcStride + c4);
    *(float4*)&Ts[r + i * 16][c4] = v;
  }
  __syncthreads();
#pragma unroll
  for (int i = 0; i < 4; ++i) {
    const int crow = r + i * 16;  // output row (source col)
    uint2 pk;
    pk.x = (uint32)f2bf(Ts[c4 + 0][crow]) | ((uint32)f2bf(Ts[c4 + 1][crow]) << 16);
    pk.y = (uint32)f2bf(Ts[c4 + 2][crow]) | ((uint32)f2bf(Ts[c4 + 3][crow]) << 16);
    *(uint2*)(dst + (size_t)crow * D_MODEL + d0 + c4) = pk;
  }
}

// ---------------------------------------------------------------------------
// MFMA GEMM 1: [xb 8192x2048 bf16] @ [Wt^T] -> Q/K/V.  cols: 0..2047 Q,
// 2048..2303 K, 2304..2559 V (written transposed Vt[b][h][s]).
// XCD-aware bijective block swizzle (T1) for L2 panel reuse.
// ---------------------------------------------------------------------------
__global__ __launch_bounds__(256) void gemm_qkv_mfma(
    const u16* __restrict__ xb, const u16* __restrict__ Wt,
    u16* __restrict__ Qb, u16* __restrict__ Kb, u16* __restrict__ Vt) {
  __shared__ u16 Asm[128][32];
  __shared__ u16 Bsm[128][32];
  const int t = threadIdx.x;
  const int w = t >> 6, l = t & 63, quad = l >> 4, lq = l & 15;
  const int wm = w & 1, wn = w >> 1;
  // XCD swizzle: nwg = 20*64 = 1280 (%8==0 -> bijective).
  const int lb = blockIdx.x + 20 * blockIdx.y;
  const int sw = (lb & 7) * 160 + (lb >> 3);
  const int col0 = (sw % 20) * 128, row0 = (sw / 20) * 128;
  const u16* ga0 = xb + (size_t)(row0 + (t >> 2)) * D_MODEL + (t & 3) * 8;
  const u16* ga1 = ga0 + (size_t)64 * D_MODEL;
  const u16* gb0 = Wt + (size_t)(col0 + (t >> 2)) * D_MODEL + (t & 3) * 8;
  const u16* gb1 = gb0 + (size_t)64 * D_MODEL;
  u16* lA0 = &Asm[0][0] + t * 8;
  u16* lA1 = lA0 + 2048;
  u16* lB0 = &Bsm[0][0] + t * 8;
  u16* lB1 = lB0 + 2048;
  f32x4 acc[4][4];
#pragma unroll
  for (int i = 0; i < 4; ++i)
#pragma unroll
    for (int j = 0; j < 4; ++j) acc[i][j] = (f32x4){0.f, 0.f, 0.f, 0.f};
  for (int k0 = 0; k0 < D_MODEL; k0 += 32) {
    gload16(ga0 + k0, lA0);
    gload16(ga1 + k0, lA1);
    gload16(gb0 + k0, lB0);
    gload16(gb1 + k0, lB1);
    __syncthreads();
    short8 af[4], bf[4];
#pragma unroll
    for (int i = 0; i < 4; ++i)
      af[i] = *(const short8*)&Asm[wm * 64 + i * 16 + lq][quad * 8];
#pragma unroll
    for (int j = 0; j < 4; ++j)
      bf[j] = *(const short8*)&Bsm[wn * 64 + j * 16 + lq][quad * 8];
#pragma unroll
    for (int i = 0; i < 4; ++i)
#pragma unroll
      for (int j = 0; j < 4; ++j)
        acc[i][j] =
            __builtin_amdgcn_mfma_f32_16x16x32_bf16(af[i], bf[j], acc[i][j], 0, 0, 0);
    __syncthreads();
  }
  const int b = row0 >> 12, sbase = row0 & 4095;
#pragma unroll
  for (int i = 0; i < 4; ++i) {
    const int rowloc = wm * 64 + i * 16 + quad * 4;
#pragma unroll
    for (int j = 0; j < 4; ++j) {
      const int col = col0 + wn * 64 + j * 16 + lq;
      if (col < 2048) {
#pragma unroll
        for (int r = 0; r < 4; ++r)
          Qb[(size_t)(row0 + rowloc + r) * 2048 + col] = f2bf(acc[i][j][r]);
      } else if (col < 2304) {
#pragma unroll
        for (int r = 0; r < 4; ++r)
          Kb[(size_t)(row0 + rowloc + r) * HDIM + (col - 2048)] =
              f2bf(acc[i][j][r]);
      } else {
        *(uint2*)(Vt + ((size_t)b * HDIM + col - 2304) * T_SEQ + sbase + rowloc) =
            pack4(acc[i][j]);
      }
    }
  }
}

// ---------------------------------------------------------------------------
// RoPE (in-place on bf16 Q and K) + query scaling by H^-0.5.
// ---------------------------------------------------------------------------
__global__ __launch_bounds__(256) void rope_kernel(u16* __restrict__ Qb,
                                                   u16* __restrict__ Kb,
                                                   const int* __restrict__ segpos) {
  const int bt = blockIdx.x;
  const int tid = threadIdx.x;
  const float fpos = (float)segpos[bt];
  const float k_ln = 9.210340371976184f / 128.0f;  // ln(10000)/(H/2)
  for (int p = tid; p < 1024; p += 256) {
    const int n = p >> 7, i = p & 127;
    const size_t base = (size_t)bt * (N_HEADS * HDIM) + (size_t)n * HDIM;
    const float th = fpos * expf(-(float)i * k_ln);
    float s, c;
    sincosf(th, &s, &c);
    const float f1 = bf2f(Qb[base + i]);
    const float f2 = bf2f(Qb[base + i + 128]);
    Qb[base + i] = f2bf((f1 * c - f2 * s) * 0.0625f);
    Qb[base + i + 128] = f2bf((f2 * c + f1 * s) * 0.0625f);
  }
  if (tid < 128) {
    const int i = tid;
    const size_t base = (size_t)bt * HDIM;
    const float th = fpos * expf(-(float)i * k_ln);
    float s, c;
    sincosf(th, &s, &c);
    const float f1 = bf2f(Kb[base + i]);
    const float f2 = bf2f(Kb[base + i + 128]);
    Kb[base + i] = f2bf(f1 * c - f2 * s);
    Kb[base + i + 128] = f2bf(f2 * c + f1 * s);
  }
}

// ---------------------------------------------------------------------------
// MFMA flash attention (causal, MQA) — Round 10 resubmit: R6-verified
// structure (265us, best measured). R8/R9 post-mortems: 32q/wave halves LDS
// traffic but forces single-tile blocks; concurrent co-resident pairs finish
// at max (not sum), so the causal triangle cannot be balanced without an
// s-split two-pass — R9 makespan was the qt=31 block's 128 iters at 1
// effective block/CU (Occupancy 12.5%). R6's 16q/wave + SEQUENTIAL
// complementary pair {63-bid, bid} gives every block exactly 130 iters and
// 2 blocks/CU (Occupancy 22%). Restored verbatim:
//  * swapped QK^T (mfma(K,Q)); K chunk-XOR swizzle; V chunk-XOR swizzle
//  * global_load_lds double-buffer, counted vmcnt(8)
//  * shfl_xor reduces + select-network P exchange; defer-max; setprio
// ---------------------------------------------------------------------------
__global__ __launch_bounds__(256, 2) void attn_mfma(const u16* __restrict__ Qb,
                                                    const u16* __restrict__ Kb,
                                                    const u16* __restrict__ Vt,
                                                    u16* __restrict__ Eb) {
  __shared__ u16 KsB[2][8192];  // [buf] 32 s-rows x 256 h (16B chunks swizzled)
  __shared__ u16 VsB[2][8192];  // [buf] 256 h-rows x 32 s (16B chunks swizzled)
  const int t = threadIdx.x;
  const int w = t >> 6, l = t & 63;
  const int quad = l >> 4, lq = l & 15;
  const int sx = lq & 7;
  const int bid = blockIdx.x;  // 0..31
  const int n = blockIdx.y, b = blockIdx.z;
  const u16* kgbase = Kb + (size_t)b * T_SEQ * HDIM;
  const u16* vgbase = Vt + (size_t)b * HDIM * T_SEQ;

  // Per-thread staging geometry: 4 K-chunks + 4 V-chunks of 16B per s-tile.
  // LDS is written linearly (wave-uniform base + lane*16); both K and V
  // carry their inverse swizzle on the global source address.
  int koff[4], voff[4], ldo[4];
#pragma unroll
  for (int p = 0; p < 4; ++p) {
    const int cid = w * 4 + p;              // 16 chunks of 1KB per 16KB tile
    const int krow = 2 * cid + (l >> 5);    // K row 0..31
    const int kchk = (l & 31) ^ (krow & 7); // swizzled 16B chunk within row
    koff[p] = krow * HDIM + kchk * 8;
    const int s_ = cid * 64 + l;            // physical 16B chunk 0..1023
    const int c_ = s_ ^ ((s_ >> 3) & 7);    // logical chunk (involution)
    voff[p] = (c_ >> 2) * T_SEQ + (c_ & 3) * 8;  // V h-row, s-chunk
    ldo[p] = cid * 512 + l * 8;             // u16 offset inside 16KB buffer
  }
  // V read-side swizzled per-lane offset (constant across ntl/iter):
  const int vlx = (lq * 32 + quad * 8) ^ ((lq >> 1) << 3);

  auto stage = [&](int buf, int s0) {
#pragma unroll
    for (int p = 0; p < 4; ++p)
      gload16(kgbase + (size_t)s0 * HDIM + koff[p], &KsB[buf][ldo[p]]);
#pragma unroll
    for (int p = 0; p < 4; ++p)
      gload16(vgbase + (size_t)voff[p] + s0, &VsB[buf][ldo[p]]);
  };

#pragma unroll 1
  for (int ti = 0; ti < 2; ++ti) {
    const int qt = ti ? bid : 63 - bid;  // heavy tile first
    const int q0 = qt * 64;
    const int wrow0 = q0 + w * 16;

    // Q fragments: 8 chunks of K=32 head-dims, in registers for this tile.
    short8 qf[8];
    {
      const u16* qbase = Qb +
          (((size_t)b * T_SEQ + wrow0 + lq) * N_HEADS + n) * HDIM + quad * 8;
#pragma unroll
      for (int c = 0; c < 8; ++c) qf[c] = *(const short8*)(qbase + c * 32);
    }
    stage(0, 0);

    f32x4 O[16];
#pragma unroll
    for (int i = 0; i < 16; ++i) O[i] = (f32x4){0.f, 0.f, 0.f, 0.f};
    float m_i = -1e30f, l_i = 0.f;

    const int nst = 2 * qt + 2;
    int cur = 0;
#pragma unroll 1
    for (int st = 0; st < nst; ++st) {
      const int s0 = st * 32;
      if (st + 1 < nst) {
        stage(cur ^ 1, s0 + 32);
        // current tile's 8 loads are the 8-before-last -> counted wait keeps
        // the prefetch in flight across the barrier.
        asm volatile("s_waitcnt vmcnt(8)" ::: "memory");
      } else {
        asm volatile("s_waitcnt vmcnt(0)" ::: "memory");
      }
      __builtin_amdgcn_s_barrier();
      if (s0 <= wrow0 + 15) {  // wave-uniform skip of fully-masked tiles
        const u16* Kc = &KsB[cur][0];
        f32x4 sa0 = (f32x4){0.f, 0.f, 0.f, 0.f};
        f32x4 sa1 = (f32x4){0.f, 0.f, 0.f, 0.f};
        __builtin_amdgcn_s_setprio(1);
#pragma unroll
        for (int c = 0; c < 8; ++c) {
          const int cb = ((c * 4 + quad) ^ sx) * 8;
          short8 k0 = *(const short8*)&Kc[lq * 256 + cb];
          short8 k1 = *(const short8*)&Kc[(16 + lq) * 256 + cb];
          // swapped operands: lane holds S[q=lq][s=quad*4+r (+16)]
          sa0 = __builtin_amdgcn_mfma_f32_16x16x32_bf16(k0, qf[c], sa0, 0, 0, 0);
          sa1 = __builtin_amdgcn_mfma_f32_16x16x32_bf16(k1, qf[c], sa1, 0, 0, 0);
        }
        __builtin_amdgcn_s_setprio(0);
        if (s0 + 31 > wrow0) {  // diagonal tiles: causal mask (s > q)
          const int qrow = wrow0 + lq;
#pragma unroll
          for (int r = 0; r < 4; ++r) {
            if (s0 + quad * 4 + r > qrow) sa0[r] = -1e30f;
            if (s0 + 16 + quad * 4 + r > qrow) sa1[r] = -1e30f;
          }
        }
        // row max (row = lq, reduce across the 4 quad replicas)
        float mx = fmaxf(fmaxf(fmaxf(sa0[0], sa0[1]), fmaxf(sa0[2], sa0[3])),
                         fmaxf(fmaxf(sa1[0], sa1[1]), fmaxf(sa1[2], sa1[3])));
        mx = fmaxf(mx, __shfl_xor(mx, 16));
        mx = fmaxf(mx, __shfl_xor(mx, 32));
        // defer-max (T13): only rescale when some row grew by > 8
        if (!__all(mx - m_i <= 8.f)) {
          const float mnew = fmaxf(m_i, mx);
          const float a = __expf(m_i - mnew);
          l_i *= a;
          m_i = mnew;
#pragma unroll
          for (int r = 0; r < 4; ++r) {
            const float ar = __shfl(a, quad * 4 + r);  // a of q-row quad*4+r
#pragma unroll
            for (int ntl = 0; ntl < 16; ++ntl) O[ntl][r] *= ar;
          }
        }
        const float p0 = __expf(sa0[0] - m_i), p1 = __expf(sa0[1] - m_i);
        const float p2 = __expf(sa0[2] - m_i), p3 = __expf(sa0[3] - m_i);
        const float p4 = __expf(sa1[0] - m_i), p5 = __expf(sa1[1] - m_i);
        const float p6 = __expf(sa1[2] - m_i), p7 = __expf(sa1[3] - m_i);
        float rs = ((p0 + p1) + (p2 + p3)) + ((p4 + p5) + (p6 + p7));
        rs += __shfl_xor(rs, 16);
        rs += __shfl_xor(rs, 32);
        l_i += rs;
        // Pack P to bf16 and build the PV A-fragment in-register.
        // Local words: a0=(cols 4g,4g+1) a1=(4g+2,4g+3) b0=(16+4g,..) b1=(..).
        // Target lane g needs cols 8g..8g+7. Two-step quad exchange:
        //   step1 xor32: g<2 send b-words, g>=2 send a-words
        //   step2 xor16: g0,g3 send step-1 words; g1 sends a; g2 sends b
        const uint32 a0 = pkbf(p0, p1), a1 = pkbf(p2, p3);
        const uint32 b0 = pkbf(p4, p5), b1 = pkbf(p6, p7);
        const uint32 s10 = (quad < 2) ? b0 : a0;
        const uint32 s11 = (quad < 2) ? b1 : a1;
        const uint32 r10 = __shfl_xor(s10, 32);
        const uint32 r11 = __shfl_xor(s11, 32);
        const bool sR = (quad == 0) || (quad == 3);
        const uint32 s20 = sR ? r10 : ((quad == 1) ? a0 : b0);
        const uint32 s21 = sR ? r11 : ((quad == 1) ? a1 : b1);
        const uint32 r20 = __shfl_xor(s20, 16);
        const uint32 r21 = __shfl_xor(s21, 16);
        const uint32 w0 = (quad == 0) ? a0 : (quad == 2) ? r10 : r20;
        const uint32 w1 = (quad == 0) ? a1 : (quad == 2) ? r11 : r21;
        const uint32 w2 = (quad == 1) ? r10 : (quad == 3) ? b0 : r20;
        const uint32 w3 = (quad == 1) ? r11 : (quad == 3) ? b1 : r21;
        const u32x4 pw = (u32x4){w0, w1, w2, w3};
        const short8 pf = __builtin_bit_cast(short8, pw);
        const u16* Vc = &VsB[cur][vlx];
        __builtin_amdgcn_s_setprio(1);
#pragma unroll
        for (int ntl = 0; ntl < 16; ++ntl) {
          short8 vf = *(const short8*)&Vc[ntl * 512];
          O[ntl] = __builtin_amdgcn_mfma_f32_16x16x32_bf16(pf, vf, O[ntl], 0, 0, 0);
        }
        __builtin_amdgcn_s_setprio(0);
      }
      __builtin_amdgcn_s_barrier();  // reads done before next-iter overwrite
      cur ^= 1;
    }
    // epilogue: normalize, store encoded bf16 for this tile
    const float inv = 1.0f / l_i;
    float invq[4];
#pragma unroll
    for (int r = 0; r < 4; ++r) invq[r] = __shfl(inv, quad * 4 + r);
    u16* ebase =
        Eb + (((size_t)b * T_SEQ + wrow0 + quad * 4) * N_HEADS + n) * HDIM + lq;
#pragma unroll
    for (int ntl = 0; ntl < 16; ++ntl)
#pragma unroll
      for (int r = 0; r < 4; ++r)
        ebase[(size_t)r * (N_HEADS * HDIM) + ntl * 16] = f2bf(O[ntl][r] * invq[r]);
  }
}

// ---------------------------------------------------------------------------
// MFMA GEMM 2: out[8192x2048 f32] = Eb(bf16) @ Owt^T.
// XCD-aware bijective block swizzle (T1).
// ---------------------------------------------------------------------------
__global__ __launch_bounds__(256) void gemm_out_mfma(const u16* __restrict__ E,
                                                     const u16* __restrict__ Owt,
                                                     float* __restrict__ out) {
  __shared__ u16 Asm[128][32];
  __shared__ u16 Bsm[128][32];
  const int t = threadIdx.x;
  const int w = t >> 6, l = t & 63, quad = l >> 4, lq = l & 15;
  const int wm = w & 1, wn = w >> 1;
  // XCD swizzle: nwg = 16*64 = 1024 (%8==0 -> bijective).
  const int lb = blockIdx.x + 16 * blockIdx.y;
  const int sw = (lb & 7) * 128 + (lb >> 3);
  const int col0 = (sw % 16) * 128, row0 = (sw / 16) * 128;
  const u16* ga0 = E + (size_t)(row0 + (t >> 2)) * D_MODEL + (t & 3) * 8;
  const u16* ga1 = ga0 + (size_t)64 * D_MODEL;
  const u16* gb0 = Owt + (size_t)(col0 + (t >> 2)) * D_MODEL + (t & 3) * 8;
  const u16* gb1 = gb0 + (size_t)64 * D_MODEL;
  u16* lA0 = &Asm[0][0] + t * 8;
  u16* lA1 = lA0 + 2048;
  u16* lB0 = &Bsm[0][0] + t * 8;
  u16* lB1 = lB0 + 2048;
  f32x4 acc[4][4];
#pragma unroll
  for (int i = 0; i < 4; ++i)
#pragma unroll
    for (int j = 0; j < 4; ++j) acc[i][j] = (f32x4){0.f, 0.f, 0.f, 0.f};
  for (int k0 = 0; k0 < D_MODEL; k0 += 32) {
    gload16(ga0 + k0, lA0);
    gload16(ga1 + k0, lA1);
    gload16(gb0 + k0, lB0);
    gload16(gb1 + k0, lB1);
    __syncthreads();
    short8 af[4], bf[4];
#pragma unroll
    for (int i = 0; i < 4; ++i)
      af[i] = *(const short8*)&Asm[wm * 64 + i * 16 + lq][quad * 8];
#pragma unroll
    for (int j = 0; j < 4; ++j)
      bf[j] = *(const short8*)&Bsm[wn * 64 + j * 16 + lq][quad * 8];
#pragma unroll
    for (int i = 0; i < 4; ++i)
#pragma unroll
      for (int j = 0; j < 4; ++j)
        acc[i][j] =
            __builtin_amdgcn_mfma_f32_16x16x32_bf16(af[i], bf[j], acc[i][j], 0, 0, 0);
    __syncthreads();
  }
#pragma unroll
  for (int i = 0; i < 4; ++i) {
    const int row = row0 + wm * 64 + i * 16 + quad * 4;
#pragma unroll
    for (int j = 0; j < 4; ++j) {
      const int col = col0 + wn * 64 + j * 16 + lq;
#pragma unroll
      for (int r = 0; r < 4; ++r)
        out[(size_t)(row + r) * D_MODEL + col] = acc[i][j][r];
    }
  }
}

// ---------------------------------------------------------------------------
extern "C" void kernel_launch(void* const* d_in, const int* in_sizes, int n_in,
                              void* d_out, int out_size, void* d_ws,
                              size_t ws_size, hipStream_t stream) {
  const float* x = (const float*)d_in[0];
  const int* segpos = (const int*)d_in[1];
  // d_in[2] = attn_mask (causal tril) — analytic, not read.
  const float* qw = (const float*)d_in[3];
  const float* kvw = (const float*)d_in[4];
  const float* ow = (const float*)d_in[5];
  float* out = (float*)d_out;

  char* ws = (char*)d_ws;
  u16* Qb = (u16*)ws;                                    // 32 MiB
  u16* Kb = (u16*)(ws + (size_t)33554432);               // 4 MiB
  u16* Vt = (u16*)(ws + (size_t)37748736);               // 4 MiB (transposed)
  u16* xb = (u16*)(ws + (size_t)41943040);               // 32 MiB (aliases Eb)
  u16* Eb = xb;  // xb dead after gemm_qkv_mfma
  u16* Wt = (u16*)(ws + (size_t)75497472);               // 10 MiB
  u16* Owt = (u16*)(ws + (size_t)85983232);              // 8 MiB  (total 90 MiB)

  hipLaunchKernelGGL(convert_x, dim3(16384), dim3(256), 0, stream, x, xb);
  hipLaunchKernelGGL(prep_weights, dim3(40, 32, 2), dim3(256), 0, stream, qw,
                     kvw, ow, Wt, Owt);
  hipLaunchKernelGGL(gemm_qkv_mfma, dim3(20, 64), dim3(256), 0, stream, xb, Wt,
                     Qb, Kb, Vt);
  hipLaunchKernelGGL(rope_kernel, dim3(8192), dim3(256), 0, stream, Qb, Kb,
                     segpos);
  hipLaunchKernelGGL(attn_mfma, dim3(32, N_HEADS, 2), dim3(256), 0, stream, Qb,
                     Kb, Vt, Eb);
  hipLaunchKernelGGL(gemm_out_mfma, dim3(16, 64), dim3(256), 0, stream, Eb, Owt,
                     out);
}

// Round 12
// 663.578 us; speedup vs baseline: 1.1811x; 1.0426x over previous
//
#include <hip/hip_runtime.h>

// Problem constants: B=2, T=4096, D=2048, N=8 heads, K=1 kv-head, H=256
#define T_SEQ 4096
#define D_MODEL 2048
#define N_HEADS 8
#define HDIM 256

typedef unsigned int uint32;
typedef unsigned short u16;
typedef __attribute__((ext_vector_type(8))) short short8;  // 8 bf16 (4 VGPRs)
typedef __attribute__((ext_vector_type(4))) float f32x4;
typedef __attribute__((ext_vector_type(4))) uint32 u32x4;

__device__ __forceinline__ float bf2f(u16 v) {
  return __uint_as_float(((uint32)v) << 16);
}
__device__ __forceinline__ u16 f2bf(float f) {
  uint32 u = __float_as_uint(f);
  u += 0x7fffu + ((u >> 16) & 1u);  // round-to-nearest-even
  return (u16)(u >> 16);
}
__device__ __forceinline__ uint32 pkbf(float x, float y) {
  return (uint32)f2bf(x) | ((uint32)f2bf(y) << 16);
}
__device__ __forceinline__ uint2 pack4(const f32x4 v) {
  uint2 r;
  r.x = (uint32)f2bf(v[0]) | ((uint32)f2bf(v[1]) << 16);
  r.y = (uint32)f2bf(v[2]) | ((uint32)f2bf(v[3]) << 16);
  return r;
}
// async global->LDS, 16B per lane; LDS dest must be lane-contiguous.
__device__ __forceinline__ void gload16(const u16* g, u16* l) {
  __builtin_amdgcn_global_load_lds(
      (const __attribute__((address_space(1))) unsigned int*)g,
      (__attribute__((address_space(3))) unsigned int*)l, 16, 0, 0);
}

// ---------------------------------------------------------------------------
// Prep 1: x (f32) -> xb (bf16), row-major [8192][2048].
// ---------------------------------------------------------------------------
__global__ __launch_bounds__(256) void convert_x(const float* __restrict__ x,
                                                 u16* __restrict__ xb) {
  const int idx = blockIdx.x * 256 + threadIdx.x;  // 4 elems each
  float4 v = *(const float4*)(x + (size_t)idx * 4);
  uint2 pk;
  pk.x = (uint32)f2bf(v.x) | ((uint32)f2bf(v.y) << 16);
  pk.y = (uint32)f2bf(v.z) | ((uint32)f2bf(v.w) << 16);
  *(uint2*)(xb + (size_t)idx * 4) = pk;
}

// ---------------------------------------------------------------------------
// Prep 2: transpose+convert weights to bf16 B^T layouts:
//   z=0: W_all[d][c] (c<2048: qw head c>>8 col c&255; else kv) -> Wt[c][d]
//   z=1: ow[k][d] (k = n*256+h)                                -> Owt[d][k]
// ---------------------------------------------------------------------------
__global__ __launch_bounds__(256) void prep_weights(
    const float* __restrict__ qw, const float* __restrict__ kvw,
    const float* __restrict__ ow, u16* __restrict__ Wt, u16* __restrict__ Owt) {
  __shared__ float Ts[64][65];
  const int t = threadIdx.x;
  const int tx = blockIdx.x, ty = blockIdx.y, z = blockIdx.z;
  const float* src;
  int srcStride;
  u16* dst;
  if (z == 0) {
    const int c0 = tx * 64;
    const float* base = (c0 < 2048)
                            ? qw + (size_t)(c0 >> 8) * D_MODEL * HDIM
                            : kvw + (size_t)((c0 - 2048) >> 8) * D_MODEL * HDIM;
    src = base + (c0 & 255);
    srcStride = HDIM;
    dst = Wt + (size_t)c0 * D_MODEL;
  } else {
    if (tx >= 32) return;
    src = ow + tx * 64;
    srcStride = D_MODEL;
    dst = Owt + (size_t)tx * 64 * D_MODEL;
  }
  const int d0 = ty * 64;
  const int r = t >> 4, c4 = (t & 15) * 4;
#pragma unroll
  for (int i = 0; i < 4; ++i) {
    float4 v = *(const float4*)(src + (size_t)(d0 + r + i * 16) * srcStride + c4);
    *(float4*)&Ts[r + i * 16][c4] = v;
  }
  __syncthreads();
#pragma unroll
  for (int i = 0; i < 4; ++i) {
    const int crow = r + i * 16;  // output row (source col)
    uint2 pk;
    pk.x = (uint32)f2bf(Ts[c4 + 0][crow]) | ((uint32)f2bf(Ts[c4 + 1][crow]) << 16);
    pk.y = (uint32)f2bf(Ts[c4 + 2][crow]) | ((uint32)f2bf(Ts[c4 + 3][crow]) << 16);
    *(uint2*)(dst + (size_t)crow * D_MODEL + d0 + c4) = pk;
  }
}

// ---------------------------------------------------------------------------
// Round 12: 256x256 multi-phase GEMM core (T2+T3+T4+T5).
// BM=BN=256, BK=32; 512 threads = 8 waves (2M x 4N); per-wave out 128x64.
// LDS 64KB: SB[2 dbuf][A 8192 u16 | B 8192 u16]; rows of 32 u16 = 4 chunks
// of 16B, chunk-XOR swizzled: phys = log ^ ((row>>1)&3) — conflict-free
// ds_read_b128 (16-lane groups hit all 8 bank groups x2). Inverse swizzle
// applied on the GLOBAL source address at staging (linear LDS dest).
// Per K-tile: {stage A-halves(t+1); vmcnt(2) counted; barrier; ds_read
// af0-3+bf0-3; 16 MFMA; stage B-halves(t+1); ds_read af4-7; 16 MFMA;
// barrier}. vmcnt never drains mid-loop; buffer re-staged only after the
// end-of-tile barrier that follows all reads' retirement.
// ---------------------------------------------------------------------------
__device__ __forceinline__ void gemm256_core(const u16* __restrict__ A,
                                             const u16* __restrict__ B,
                                             int row0, int col0,
                                             u16 (&SB)[2][16384],
                                             f32x4 (&acc)[8][4]) {
  const int t = threadIdx.x;
  const int l = t & 63, quad = l >> 4, lq = l & 15;
  const int w = t >> 6, wm = w >> 2, wn = w & 3;
  // staging geometry: thread t stages one 16B chunk per half per tile
  const int crow = t >> 2;                               // row 0..127 in half
  const int cch = ((t & 3) ^ ((t >> 3) & 3)) * 8;        // logical chunk (u16)
  const u16* pA0 = A + (size_t)(row0 + crow) * 2048 + cch;
  const u16* pA1 = pA0 + (size_t)128 * 2048;
  const u16* pB0 = B + (size_t)(col0 + crow) * 2048 + cch;
  const u16* pB1 = pB0 + (size_t)128 * 2048;
  const int t8 = t * 8;
  // read geometry
  const int ckk = (quad ^ ((lq >> 1) & 3)) * 8;          // swizzled k-chunk
  const int aBase = (wm * 128 + lq) * 32 + ckk;
  const int bBase = 8192 + (wn * 64 + lq) * 32 + ckk;

  // prologue: tile 0 into buf 0 (4 loads/thread)
  gload16(pA0, &SB[0][t8]);
  gload16(pA1, &SB[0][4096 + t8]);
  gload16(pB0, &SB[0][8192 + t8]);
  gload16(pB1, &SB[0][12288 + t8]);
#pragma unroll
  for (int i = 0; i < 8; ++i)
#pragma unroll
    for (int j = 0; j < 4; ++j) acc[i][j] = (f32x4){0.f, 0.f, 0.f, 0.f};

  int cur = 0;
#pragma unroll 1
  for (int kt = 0; kt < 64; ++kt) {
    const int kn = (kt + 1) * 32;
    short8 bf[4];
    // ---- phase 0: stage next A-halves, counted wait, compute upper half ----
    if (kt < 63) {
      gload16(pA0 + kn, &SB[cur ^ 1][t8]);
      gload16(pA1 + kn, &SB[cur ^ 1][4096 + t8]);
      asm volatile("s_waitcnt vmcnt(2)" ::: "memory");  // tile kt's 4 landed
    } else {
      asm volatile("s_waitcnt vmcnt(0)" ::: "memory");
    }
    __builtin_amdgcn_s_barrier();
    {
      const u16* S = &SB[cur][0];
      short8 af[4];
#pragma unroll
      for (int i = 0; i < 4; ++i) af[i] = *(const short8*)&S[aBase + i * 512];
#pragma unroll
      for (int j = 0; j < 4; ++j) bf[j] = *(const short8*)&S[bBase + j * 512];
      __builtin_amdgcn_s_setprio(1);
#pragma unroll
      for (int i = 0; i < 4; ++i)
#pragma unroll
        for (int j = 0; j < 4; ++j)
          acc[i][j] =
              __builtin_amdgcn_mfma_f32_16x16x32_bf16(af[i], bf[j], acc[i][j], 0, 0, 0);
      __builtin_amdgcn_s_setprio(0);
    }
    // ---- phase 1: stage next B-halves, compute lower half ----
    if (kt < 63) {
      gload16(pB0 + kn, &SB[cur ^ 1][8192 + t8]);
      gload16(pB1 + kn, &SB[cur ^ 1][12288 + t8]);
    }
    {
      const u16* S = &SB[cur][0];
      short8 af[4];
#pragma unroll
      for (int i = 0; i < 4; ++i)
        af[i] = *(const short8*)&S[aBase + (4 + i) * 512];
      __builtin_amdgcn_s_setprio(1);
#pragma unroll
      for (int i = 0; i < 4; ++i)
#pragma unroll
        for (int j = 0; j < 4; ++j)
          acc[4 + i][j] =
              __builtin_amdgcn_mfma_f32_16x16x32_bf16(af[i], bf[j], acc[4 + i][j], 0, 0, 0);
      __builtin_amdgcn_s_setprio(0);
    }
    __builtin_amdgcn_s_barrier();  // all reads of buf cur retired
    cur ^= 1;
  }
}

// ---------------------------------------------------------------------------
// MFMA GEMM 1: [xb 8192x2048 bf16] @ [Wt^T] -> Q/K/V.  256x256 tiles.
// Col-blocks: 0..7 pure Q, 8 pure K, 9 pure V (uniform per block).
// Grid 10x32 = 320 blocks, XCD-bijective swizzle (320%8==0).
// ---------------------------------------------------------------------------
__global__ __launch_bounds__(512, 2) void gemm_qkv_mfma(
    const u16* __restrict__ xb, const u16* __restrict__ Wt,
    u16* __restrict__ Qb, u16* __restrict__ Kb, u16* __restrict__ Vt) {
  __shared__ u16 SB[2][16384];
  const int lb = blockIdx.x + 10 * blockIdx.y;
  const int sw = (lb & 7) * 40 + (lb >> 3);
  const int col0 = (sw % 10) * 256, row0 = (sw / 10) * 256;
  f32x4 acc[8][4];
  gemm256_core(xb, Wt, row0, col0, SB, acc);

  const int t = threadIdx.x;
  const int l = t & 63, quad = l >> 4, lq = l & 15;
  const int w = t >> 6, wm = w >> 2, wn = w & 3;
  const int rl = wm * 128 + quad * 4;
  const int cl = wn * 64 + lq;
  if (col0 < 2048) {
#pragma unroll
    for (int mf = 0; mf < 8; ++mf)
#pragma unroll
      for (int nf = 0; nf < 4; ++nf)
#pragma unroll
        for (int r = 0; r < 4; ++r)
          Qb[(size_t)(row0 + rl + mf * 16 + r) * 2048 + col0 + cl + nf * 16] =
              f2bf(acc[mf][nf][r]);
  } else if (col0 == 2048) {
#pragma unroll
    for (int mf = 0; mf < 8; ++mf)
#pragma unroll
      for (int nf = 0; nf < 4; ++nf)
#pragma unroll
        for (int r = 0; r < 4; ++r)
          Kb[(size_t)(row0 + rl + mf * 16 + r) * HDIM + cl + nf * 16] =
              f2bf(acc[mf][nf][r]);
  } else {  // V, stored transposed Vt[b][h][s]
    const int b = row0 >> 12, sb = row0 & 4095;
#pragma unroll
    for (int mf = 0; mf < 8; ++mf)
#pragma unroll
      for (int nf = 0; nf < 4; ++nf)
        *(uint2*)(Vt + ((size_t)b * HDIM + cl + nf * 16) * T_SEQ + sb + rl +
                  mf * 16) = pack4(acc[mf][nf]);
  }
}

// ---------------------------------------------------------------------------
// MFMA GEMM 2: out[8192x2048 f32] = Eb(bf16) @ Owt^T.  256x256 tiles.
// Grid 8x32 = 256 blocks (1 clean round), XCD-bijective swizzle.
// ---------------------------------------------------------------------------
__global__ __launch_bounds__(512, 2) void gemm_out_mfma(
    const u16* __restrict__ E, const u16* __restrict__ Owt,
    float* __restrict__ out) {
  __shared__ u16 SB[2][16384];
  const int lb = blockIdx.x + 8 * blockIdx.y;
  const int sw = (lb & 7) * 32 + (lb >> 3);
  const int col0 = (sw % 8) * 256, row0 = (sw / 8) * 256;
  f32x4 acc[8][4];
  gemm256_core(E, Owt, row0, col0, SB, acc);

  const int t = threadIdx.x;
  const int l = t & 63, quad = l >> 4, lq = l & 15;
  const int w = t >> 6, wm = w >> 2, wn = w & 3;
  const int rl = wm * 128 + quad * 4;
  const int cl = wn * 64 + lq;
#pragma unroll
  for (int mf = 0; mf < 8; ++mf)
#pragma unroll
    for (int nf = 0; nf < 4; ++nf)
#pragma unroll
      for (int r = 0; r < 4; ++r)
        out[(size_t)(row0 + rl + mf * 16 + r) * 2048 + col0 + cl + nf * 16] =
            acc[mf][nf][r];
}

// ---------------------------------------------------------------------------
// RoPE (in-place on bf16 Q and K) + query scaling by H^-0.5.
// ---------------------------------------------------------------------------
__global__ __launch_bounds__(256) void rope_kernel(u16* __restrict__ Qb,
                                                   u16* __restrict__ Kb,
                                                   const int* __restrict__ segpos) {
  const int bt = blockIdx.x;
  const int tid = threadIdx.x;
  const float fpos = (float)segpos[bt];
  const float k_ln = 9.210340371976184f / 128.0f;  // ln(10000)/(H/2)
  for (int p = tid; p < 1024; p += 256) {
    const int n = p >> 7, i = p & 127;
    const size_t base = (size_t)bt * (N_HEADS * HDIM) + (size_t)n * HDIM;
    const float th = fpos * expf(-(float)i * k_ln);
    float s, c;
    sincosf(th, &s, &c);
    const float f1 = bf2f(Qb[base + i]);
    const float f2 = bf2f(Qb[base + i + 128]);
    Qb[base + i] = f2bf((f1 * c - f2 * s) * 0.0625f);
    Qb[base + i + 128] = f2bf((f2 * c + f1 * s) * 0.0625f);
  }
  if (tid < 128) {
    const int i = tid;
    const size_t base = (size_t)bt * HDIM;
    const float th = fpos * expf(-(float)i * k_ln);
    float s, c;
    sincosf(th, &s, &c);
    const float f1 = bf2f(Kb[base + i]);
    const float f2 = bf2f(Kb[base + i + 128]);
    Kb[base + i] = f2bf(f1 * c - f2 * s);
    Kb[base + i + 128] = f2bf(f2 * c + f1 * s);
  }
}

// ---------------------------------------------------------------------------
// MFMA flash attention (causal, MQA) — R6-verified structure (265us),
// unchanged from Round 11.
// ---------------------------------------------------------------------------
__global__ __launch_bounds__(256, 2) void attn_mfma(const u16* __restrict__ Qb,
                                                    const u16* __restrict__ Kb,
                                                    const u16* __restrict__ Vt,
                                                    u16* __restrict__ Eb) {
  __shared__ u16 KsB[2][8192];  // [buf] 32 s-rows x 256 h (16B chunks swizzled)
  __shared__ u16 VsB[2][8192];  // [buf] 256 h-rows x 32 s (16B chunks swizzled)
  const int t = threadIdx.x;
  const int w = t >> 6, l = t & 63;
  const int quad = l >> 4, lq = l & 15;
  const int sx = lq & 7;
  const int bid = blockIdx.x;  // 0..31
  const int n = blockIdx.y, b = blockIdx.z;
  const u16* kgbase = Kb + (size_t)b * T_SEQ * HDIM;
  const u16* vgbase = Vt + (size_t)b * HDIM * T_SEQ;

  int koff[4], voff[4], ldo[4];
#pragma unroll
  for (int p = 0; p < 4; ++p) {
    const int cid = w * 4 + p;              // 16 chunks of 1KB per 16KB tile
    const int krow = 2 * cid + (l >> 5);    // K row 0..31
    const int kchk = (l & 31) ^ (krow & 7); // swizzled 16B chunk within row
    koff[p] = krow * HDIM + kchk * 8;
    const int s_ = cid * 64 + l;            // physical 16B chunk 0..1023
    const int c_ = s_ ^ ((s_ >> 3) & 7);    // logical chunk (involution)
    voff[p] = (c_ >> 2) * T_SEQ + (c_ & 3) * 8;  // V h-row, s-chunk
    ldo[p] = cid * 512 + l * 8;             // u16 offset inside 16KB buffer
  }
  // V read-side swizzled per-lane offset (constant across ntl/iter):
  const int vlx = (lq * 32 + quad * 8) ^ ((lq >> 1) << 3);

  auto stage = [&](int buf, int s0) {
#pragma unroll
    for (int p = 0; p < 4; ++p)
      gload16(kgbase + (size_t)s0 * HDIM + koff[p], &KsB[buf][ldo[p]]);
#pragma unroll
    for (int p = 0; p < 4; ++p)
      gload16(vgbase + (size_t)voff[p] + s0, &VsB[buf][ldo[p]]);
  };

#pragma unroll 1
  for (int ti = 0; ti < 2; ++ti) {
    const int qt = ti ? bid : 63 - bid;  // heavy tile first
    const int q0 = qt * 64;
    const int wrow0 = q0 + w * 16;

    // Q fragments: 8 chunks of K=32 head-dims, in registers for this tile.
    short8 qf[8];
    {
      const u16* qbase = Qb +
          (((size_t)b * T_SEQ + wrow0 + lq) * N_HEADS + n) * HDIM + quad * 8;
#pragma unroll
      for (int c = 0; c < 8; ++c) qf[c] = *(const short8*)(qbase + c * 32);
    }
    stage(0, 0);

    f32x4 O[16];
#pragma unroll
    for (int i = 0; i < 16; ++i) O[i] = (f32x4){0.f, 0.f, 0.f, 0.f};
    float m_i = -1e30f, l_i = 0.f;

    const int nst = 2 * qt + 2;
    int cur = 0;
#pragma unroll 1
    for (int st = 0; st < nst; ++st) {
      const int s0 = st * 32;
      if (st + 1 < nst) {
        stage(cur ^ 1, s0 + 32);
        asm volatile("s_waitcnt vmcnt(8)" ::: "memory");
      } else {
        asm volatile("s_waitcnt vmcnt(0)" ::: "memory");
      }
      __builtin_amdgcn_s_barrier();
      if (s0 <= wrow0 + 15) {  // wave-uniform skip of fully-masked tiles
        const u16* Kc = &KsB[cur][0];
        f32x4 sa0 = (f32x4){0.f, 0.f, 0.f, 0.f};
        f32x4 sa1 = (f32x4){0.f, 0.f, 0.f, 0.f};
        __builtin_amdgcn_s_setprio(1);
#pragma unroll
        for (int c = 0; c < 8; ++c) {
          const int cb = ((c * 4 + quad) ^ sx) * 8;
          short8 k0 = *(const short8*)&Kc[lq * 256 + cb];
          short8 k1 = *(const short8*)&Kc[(16 + lq) * 256 + cb];
          sa0 = __builtin_amdgcn_mfma_f32_16x16x32_bf16(k0, qf[c], sa0, 0, 0, 0);
          sa1 = __builtin_amdgcn_mfma_f32_16x16x32_bf16(k1, qf[c], sa1, 0, 0, 0);
        }
        __builtin_amdgcn_s_setprio(0);
        if (s0 + 31 > wrow0) {  // diagonal tiles: causal mask (s > q)
          const int qrow = wrow0 + lq;
#pragma unroll
          for (int r = 0; r < 4; ++r) {
            if (s0 + quad * 4 + r > qrow) sa0[r] = -1e30f;
            if (s0 + 16 + quad * 4 + r > qrow) sa1[r] = -1e30f;
          }
        }
        float mx = fmaxf(fmaxf(fmaxf(sa0[0], sa0[1]), fmaxf(sa0[2], sa0[3])),
                         fmaxf(fmaxf(sa1[0], sa1[1]), fmaxf(sa1[2], sa1[3])));
        mx = fmaxf(mx, __shfl_xor(mx, 16));
        mx = fmaxf(mx, __shfl_xor(mx, 32));
        if (!__all(mx - m_i <= 8.f)) {
          const float mnew = fmaxf(m_i, mx);
          const float a = __expf(m_i - mnew);
          l_i *= a;
          m_i = mnew;
#pragma unroll
          for (int r = 0; r < 4; ++r) {
            const float ar = __shfl(a, quad * 4 + r);  // a of q-row quad*4+r
#pragma unroll
            for (int ntl = 0; ntl < 16; ++ntl) O[ntl][r] *= ar;
          }
        }
        const float p0 = __expf(sa0[0] - m_i), p1 = __expf(sa0[1] - m_i);
        const float p2 = __expf(sa0[2] - m_i), p3 = __expf(sa0[3] - m_i);
        const float p4 = __expf(sa1[0] - m_i), p5 = __expf(sa1[1] - m_i);
        const float p6 = __expf(sa1[2] - m_i), p7 = __expf(sa1[3] - m_i);
        float rs = ((p0 + p1) + (p2 + p3)) + ((p4 + p5) + (p6 + p7));
        rs += __shfl_xor(rs, 16);
        rs += __shfl_xor(rs, 32);
        l_i += rs;
        const uint32 a0 = pkbf(p0, p1), a1 = pkbf(p2, p3);
        const uint32 b0 = pkbf(p4, p5), b1 = pkbf(p6, p7);
        const uint32 s10 = (quad < 2) ? b0 : a0;
        const uint32 s11 = (quad < 2) ? b1 : a1;
        const uint32 r10 = __shfl_xor(s10, 32);
        const uint32 r11 = __shfl_xor(s11, 32);
        const bool sR = (quad == 0) || (quad == 3);
        const uint32 s20 = sR ? r10 : ((quad == 1) ? a0 : b0);
        const uint32 s21 = sR ? r11 : ((quad == 1) ? a1 : b1);
        const uint32 r20 = __shfl_xor(s20, 16);
        const uint32 r21 = __shfl_xor(s21, 16);
        const uint32 w0 = (quad == 0) ? a0 : (quad == 2) ? r10 : r20;
        const uint32 w1 = (quad == 0) ? a1 : (quad == 2) ? r11 : r21;
        const uint32 w2 = (quad == 1) ? r10 : (quad == 3) ? b0 : r20;
        const uint32 w3 = (quad == 1) ? r11 : (quad == 3) ? b1 : r21;
        const u32x4 pw = (u32x4){w0, w1, w2, w3};
        const short8 pf = __builtin_bit_cast(short8, pw);
        const u16* Vc = &VsB[cur][vlx];
        __builtin_amdgcn_s_setprio(1);
#pragma unroll
        for (int ntl = 0; ntl < 16; ++ntl) {
          short8 vf = *(const short8*)&Vc[ntl * 512];
          O[ntl] = __builtin_amdgcn_mfma_f32_16x16x32_bf16(pf, vf, O[ntl], 0, 0, 0);
        }
        __builtin_amdgcn_s_setprio(0);
      }
      __builtin_amdgcn_s_barrier();  // reads done before next-iter overwrite
      cur ^= 1;
    }
    // epilogue: normalize, store encoded bf16 for this tile
    const float inv = 1.0f / l_i;
    float invq[4];
#pragma unroll
    for (int r = 0; r < 4; ++r) invq[r] = __shfl(inv, quad * 4 + r);
    u16* ebase =
        Eb + (((size_t)b * T_SEQ + wrow0 + quad * 4) * N_HEADS + n) * HDIM + lq;
#pragma unroll
    for (int ntl = 0; ntl < 16; ++ntl)
#pragma unroll
      for (int r = 0; r < 4; ++r)
        ebase[(size_t)r * (N_HEADS * HDIM) + ntl * 16] = f2bf(O[ntl][r] * invq[r]);
  }
}

// ---------------------------------------------------------------------------
extern "C" void kernel_launch(void* const* d_in, const int* in_sizes, int n_in,
                              void* d_out, int out_size, void* d_ws,
                              size_t ws_size, hipStream_t stream) {
  const float* x = (const float*)d_in[0];
  const int* segpos = (const int*)d_in[1];
  // d_in[2] = attn_mask (causal tril) — analytic, not read.
  const float* qw = (const float*)d_in[3];
  const float* kvw = (const float*)d_in[4];
  const float* ow = (const float*)d_in[5];
  float* out = (float*)d_out;

  char* ws = (char*)d_ws;
  u16* Qb = (u16*)ws;                                    // 32 MiB
  u16* Kb = (u16*)(ws + (size_t)33554432);               // 4 MiB
  u16* Vt = (u16*)(ws + (size_t)37748736);               // 4 MiB (transposed)
  u16* xb = (u16*)(ws + (size_t)41943040);               // 32 MiB (aliases Eb)
  u16* Eb = xb;  // xb dead after gemm_qkv_mfma
  u16* Wt = (u16*)(ws + (size_t)75497472);               // 10 MiB
  u16* Owt = (u16*)(ws + (size_t)85983232);              // 8 MiB  (total 90 MiB)

  hipLaunchKernelGGL(convert_x, dim3(16384), dim3(256), 0, stream, x, xb);
  hipLaunchKernelGGL(prep_weights, dim3(40, 32, 2), dim3(256), 0, stream, qw,
                     kvw, ow, Wt, Owt);
  hipLaunchKernelGGL(gemm_qkv_mfma, dim3(10, 32), dim3(512), 0, stream, xb, Wt,
                     Qb, Kb, Vt);
  hipLaunchKernelGGL(rope_kernel, dim3(8192), dim3(256), 0, stream, Qb, Kb,
                     segpos);
  hipLaunchKernelGGL(attn_mfma, dim3(32, N_HEADS, 2), dim3(256), 0, stream, Qb,
                     Kb, Vt, Eb);
  hipLaunchKernelGGL(gemm_out_mfma, dim3(8, 32), dim3(512), 0, stream, Eb, Owt,
                     out);
}